// Round 2
// baseline (21919.917 us; speedup 1.0000x reference)
//
#include <hip/hip_runtime.h>
#include <cstdint>
#include <cstddef>

// Problem constants
#define BB 32
#define TT 256
#define HID 512
// ws layout (floats)
//  x0     : 8192*350   = 2,867,200
//  xp_fw  : 8192*2048  = 16,777,216
//  xp_bw  : 16,777,216
//  out0   : 8192*1024  = 8,388,608
//  out1   : 8,388,608
//  hT     : 2 dir * 2 buf * 512*32 = 65,536
//  cbuf   : 2 dir * 512*32         = 32,768   (fallback path only)
//  bar    : 128 ints                          (persistent path)

// ---------------- embedding + concat ----------------
__global__ __launch_bounds__(256) void embed_kernel(
    const int* __restrict__ ids, const int* __restrict__ msk,
    const float* __restrict__ emb, const float* __restrict__ memb,
    float* __restrict__ x0)
{
  int bt = blockIdx.x;            // 0..8191
  int id = ids[bt];
  int m  = msk[bt];
  const float* er = emb  + (size_t)id * 300;
  const float* mr = memb + (size_t)m * 50;
  for (int d = threadIdx.x; d < 350; d += 256) {
    x0[(size_t)bt * 350 + d] = (d < 300) ? er[d] : mr[d - 300];
  }
}

// ---------------- fp32 GEMM: C(M x 2048) = A(M x K) @ W(K x 2048) + bias ----
__global__ __launch_bounds__(256) void gemm_proj(
    const float* __restrict__ A, const float* __restrict__ W,
    const float* __restrict__ bias, float* __restrict__ C,
    int M, int K)
{
  const int N = 2048;
  __shared__ float As[16][128];
  __shared__ float Bs[16][128];
  int tid = threadIdx.x;
  int m0 = blockIdx.x * 128;
  int n0 = blockIdx.y * 128;
  int ty = tid >> 4, tx = tid & 15;
  float acc[8][8];
#pragma unroll
  for (int i = 0; i < 8; ++i) {
#pragma unroll
    for (int j = 0; j < 8; ++j) acc[i][j] = 0.f;
  }
  for (int k0 = 0; k0 < K; k0 += 16) {
#pragma unroll
    for (int i = 0; i < 8; ++i) {
      int e = tid + i * 256;
      int row = e >> 4, kk = e & 15;
      float v = (k0 + kk < K) ? A[(size_t)(m0 + row) * K + k0 + kk] : 0.f;
      As[kk][row] = v;
    }
#pragma unroll
    for (int i = 0; i < 2; ++i) {
      int e = tid + i * 256;
      int kk = e >> 5, c4 = (e & 31) << 2;
      float4 v = make_float4(0.f, 0.f, 0.f, 0.f);
      if (k0 + kk < K) v = *(const float4*)(W + (size_t)(k0 + kk) * N + n0 + c4);
      *(float4*)&Bs[kk][c4] = v;
    }
    __syncthreads();
#pragma unroll
    for (int kk = 0; kk < 16; ++kk) {
      float a[8], b[8];
      *(float4*)&a[0] = *(const float4*)&As[kk][ty * 8];
      *(float4*)&a[4] = *(const float4*)&As[kk][ty * 8 + 4];
      *(float4*)&b[0] = *(const float4*)&Bs[kk][tx * 8];
      *(float4*)&b[4] = *(const float4*)&Bs[kk][tx * 8 + 4];
#pragma unroll
      for (int i = 0; i < 8; ++i) {
#pragma unroll
        for (int j = 0; j < 8; ++j) acc[i][j] = fmaf(a[i], b[j], acc[i][j]);
      }
    }
    __syncthreads();
  }
#pragma unroll
  for (int i = 0; i < 8; ++i) {
    int row = m0 + ty * 8 + i;
#pragma unroll
    for (int jv = 0; jv < 2; ++jv) {
      int col = n0 + tx * 8 + jv * 4;
      float4 o;
      o.x = acc[i][jv * 4 + 0] + bias[col + 0];
      o.y = acc[i][jv * 4 + 1] + bias[col + 1];
      o.z = acc[i][jv * 4 + 2] + bias[col + 2];
      o.w = acc[i][jv * 4 + 3] + bias[col + 3];
      *(float4*)(C + (size_t)row * N + col) = o;
    }
  }
}

// ================= persistent bidirectional LSTM layer =================
// Cooperative launch, grid=256 WGs x 256 threads, 1 WG/CU (112KB dyn LDS).
// wg<128 -> fw, wg>=128 -> bw; each WG owns 4 hidden units (16 gate cols).
// W slice resident in LDS across all 256 timesteps; c state in registers.
// Per-direction device-scope barrier (128 WGs) between steps.
__global__ __launch_bounds__(256) void lstm_persist(
    const float* __restrict__ xp_fw, const float* __restrict__ xp_bw,
    const float* __restrict__ w_fw, const float* __restrict__ w_bw,
    int din,
    const int* __restrict__ length,
    float* __restrict__ out,      // (B,T,1024)
    float* __restrict__ hT,       // [dir][2][512][32]
    int* __restrict__ bar)        // [dir*64]
{
  extern __shared__ float smem[];
  float* Wl = smem;              // [512][16]  32KB
  float* hs = smem + 512 * 16;   // [512][32]  64KB
  float* zs = hs + 512 * 32;     // [8][512]   16KB
  int tid = threadIdx.x;
  int wg = blockIdx.x;
  int dir = wg >> 7;
  int u0 = (wg & 127) << 2;
  const float* Wm = dir ? w_bw : w_fw;
  const float* xp = dir ? xp_bw : xp_fw;
  float* hbase = hT + (size_t)dir * 32768;
  int* mybar = bar + dir * 64;   // 256B apart

  // ---- load recurrent-weight slice ONCE ----
  {
    const float* wbase = Wm + (size_t)din * 2048 + u0;
#pragma unroll
    for (int kk = 0; kk < 2; ++kk) {
      int k = tid * 2 + kk;
      const float* wr = wbase + (size_t)k * 2048;
#pragma unroll
      for (int q = 0; q < 4; ++q) {
        *(float4*)&Wl[k * 16 + q * 4] = *(const float4*)(wr + q * 512);
      }
    }
  }

  // compute-phase constants
  int ks = tid >> 5;
  int tile = tid & 31;
  int c0 = (tile & 3) << 2;
  int b0 = (tile >> 2) << 2;
  int kbeg = ks << 6;
  // finalize-phase constants (tid < 128)
  int fu = tid >> 5;         // 0..3 (only valid tid<128)
  int fb = tid & 31;         // batch
  int L = length[fb];
  float creg = 0.f;          // persistent cell state for (u0+fu, fb)

  for (int t = 0; t < TT; ++t) {
    const float* hTr = hbase + (size_t)(t & 1) * 16384;
    float* hTw = hbase + (size_t)((t & 1) ^ 1) * 16384;

    // stage previous h : [512][32] linear
#pragma unroll
    for (int i = 0; i < 16; ++i) {
      int e = (tid + i * 256) * 4;
      *(float4*)&hs[e] = *(const float4*)&hTr[e];
    }
    __syncthreads();

    // partial z: thread = (ks, 4 cols, 4 batches), k-split 8
    float acc[4][4];
#pragma unroll
    for (int i = 0; i < 4; ++i) {
#pragma unroll
      for (int j = 0; j < 4; ++j) acc[i][j] = 0.f;
    }
    for (int k = kbeg; k < kbeg + 64; ++k) {
      float4 w4 = *(const float4*)&Wl[k * 16 + c0];
      float4 h4 = *(const float4*)&hs[k * 32 + b0];
      acc[0][0] = fmaf(w4.x, h4.x, acc[0][0]);
      acc[0][1] = fmaf(w4.x, h4.y, acc[0][1]);
      acc[0][2] = fmaf(w4.x, h4.z, acc[0][2]);
      acc[0][3] = fmaf(w4.x, h4.w, acc[0][3]);
      acc[1][0] = fmaf(w4.y, h4.x, acc[1][0]);
      acc[1][1] = fmaf(w4.y, h4.y, acc[1][1]);
      acc[1][2] = fmaf(w4.y, h4.z, acc[1][2]);
      acc[1][3] = fmaf(w4.y, h4.w, acc[1][3]);
      acc[2][0] = fmaf(w4.z, h4.x, acc[2][0]);
      acc[2][1] = fmaf(w4.z, h4.y, acc[2][1]);
      acc[2][2] = fmaf(w4.z, h4.z, acc[2][2]);
      acc[2][3] = fmaf(w4.z, h4.w, acc[2][3]);
      acc[3][0] = fmaf(w4.w, h4.x, acc[3][0]);
      acc[3][1] = fmaf(w4.w, h4.y, acc[3][1]);
      acc[3][2] = fmaf(w4.w, h4.z, acc[3][2]);
      acc[3][3] = fmaf(w4.w, h4.w, acc[3][3]);
    }
#pragma unroll
    for (int ci = 0; ci < 4; ++ci) {
      *(float4*)&zs[ks * 512 + (c0 + ci) * 32 + b0] =
          make_float4(acc[ci][0], acc[ci][1], acc[ci][2], acc[ci][3]);
    }
    __syncthreads();

    if (tid < 128) {
      bool active = t < L;
      int ug = u0 + fu;
      int pos = dir ? (active ? (L - 1 - t) : t) : t;
      const float* xr = xp + ((size_t)(fb * TT + pos)) * 2048 + ug;
      float z[4];
#pragma unroll
      for (int q = 0; q < 4; ++q) {
        float s = xr[(size_t)q * 512];
#pragma unroll
        for (int p = 0; p < 8; ++p) s += zs[p * 512 + (q * 4 + fu) * 32 + fb];
        z[q] = s;
      }
      float h_old = hs[ug * 32 + fb];
      float si = 1.f / (1.f + expf(-z[0]));
      float sj = tanhf(z[1]);
      float sf = 1.f / (1.f + expf(-(z[2] + 1.f)));
      float so = 1.f / (1.f + expf(-z[3]));
      float cn = sf * creg + si * sj;
      float hn = so * tanhf(cn);
      if (active) creg = cn;
      hTw[ug * 32 + fb] = active ? hn : h_old;
      out[((size_t)(fb * TT + pos)) * 1024 + dir * 512 + ug] = active ? hn : 0.f;
    }

    // per-direction device barrier
    __threadfence();
    __syncthreads();
    if (tid == 0) {
      atomicAdd(mybar, 1);
      int target = 128 * (t + 1);
      while (__hip_atomic_load(mybar, __ATOMIC_ACQUIRE,
                               __HIP_MEMORY_SCOPE_AGENT) < target) {
        __builtin_amdgcn_s_sleep(2);
      }
    }
    __syncthreads();
  }
}

// ---------------- fallback: one LSTM timestep (round-0 validated) --------
__global__ __launch_bounds__(256) void lstm_step(
    const float* __restrict__ xp_fw, const float* __restrict__ xp_bw,
    const float* __restrict__ w_fw, const float* __restrict__ w_bw,
    int din,
    const int* __restrict__ length,
    float* __restrict__ out,
    float* __restrict__ hT,
    float* __restrict__ cbuf,
    int t)
{
  extern __shared__ float smem[];
  float* Wl = smem;
  float* hs = smem + 512 * 16;
  float* zs = hs + 512 * 32;
  int tid = threadIdx.x;
  int wg = blockIdx.x;
  int dir = wg >> 7;
  int wd = wg & 127;
  int u0 = wd << 2;
  const float* Wm = dir ? w_bw : w_fw;
  const float* xp = dir ? xp_bw : xp_fw;
  const float* hTr = hT + (size_t)dir * 32768 + (size_t)(t & 1) * 16384;
  float* hTw = hT + (size_t)dir * 32768 + (size_t)((t & 1) ^ 1) * 16384;
  float* cb = cbuf + (size_t)dir * 16384;
  {
    const float* wbase = Wm + (size_t)din * 2048 + u0;
#pragma unroll
    for (int kk = 0; kk < 2; ++kk) {
      int k = tid * 2 + kk;
      const float* wr = wbase + (size_t)k * 2048;
#pragma unroll
      for (int q = 0; q < 4; ++q) {
        *(float4*)&Wl[k * 16 + q * 4] = *(const float4*)(wr + q * 512);
      }
    }
  }
#pragma unroll
  for (int i = 0; i < 16; ++i) {
    int e = (tid + i * 256) * 4;
    *(float4*)&hs[e] = *(const float4*)&hTr[e];
  }
  __syncthreads();
  int ks = tid >> 5;
  int tile = tid & 31;
  int c0 = (tile & 3) << 2;
  int b0 = (tile >> 2) << 2;
  float acc[4][4];
#pragma unroll
  for (int i = 0; i < 4; ++i) {
#pragma unroll
    for (int j = 0; j < 4; ++j) acc[i][j] = 0.f;
  }
  int kbeg = ks << 6;
  for (int k = kbeg; k < kbeg + 64; ++k) {
    float4 w4 = *(const float4*)&Wl[k * 16 + c0];
    float4 h4 = *(const float4*)&hs[k * 32 + b0];
    acc[0][0] = fmaf(w4.x, h4.x, acc[0][0]);
    acc[0][1] = fmaf(w4.x, h4.y, acc[0][1]);
    acc[0][2] = fmaf(w4.x, h4.z, acc[0][2]);
    acc[0][3] = fmaf(w4.x, h4.w, acc[0][3]);
    acc[1][0] = fmaf(w4.y, h4.x, acc[1][0]);
    acc[1][1] = fmaf(w4.y, h4.y, acc[1][1]);
    acc[1][2] = fmaf(w4.y, h4.z, acc[1][2]);
    acc[1][3] = fmaf(w4.y, h4.w, acc[1][3]);
    acc[2][0] = fmaf(w4.z, h4.x, acc[2][0]);
    acc[2][1] = fmaf(w4.z, h4.y, acc[2][1]);
    acc[2][2] = fmaf(w4.z, h4.z, acc[2][2]);
    acc[2][3] = fmaf(w4.z, h4.w, acc[2][3]);
    acc[3][0] = fmaf(w4.w, h4.x, acc[3][0]);
    acc[3][1] = fmaf(w4.w, h4.y, acc[3][1]);
    acc[3][2] = fmaf(w4.w, h4.z, acc[3][2]);
    acc[3][3] = fmaf(w4.w, h4.w, acc[3][3]);
  }
#pragma unroll
  for (int ci = 0; ci < 4; ++ci) {
    *(float4*)&zs[ks * 512 + (c0 + ci) * 32 + b0] =
        make_float4(acc[ci][0], acc[ci][1], acc[ci][2], acc[ci][3]);
  }
  __syncthreads();
  if (tid < 128) {
    int u = tid >> 5;
    int b = tid & 31;
    int L = length[b];
    bool active = t < L;
    int ug = u0 + u;
    int pos = dir ? (active ? (L - 1 - t) : t) : t;
    const float* xr = xp + ((size_t)(b * TT + pos)) * 2048 + ug;
    float z[4];
#pragma unroll
    for (int q = 0; q < 4; ++q) {
      float s = xr[(size_t)q * 512];
#pragma unroll
      for (int p = 0; p < 8; ++p) s += zs[p * 512 + (q * 4 + u) * 32 + b];
      z[q] = s;
    }
    float c_old = cb[ug * 32 + b];
    float h_old = hs[ug * 32 + b];
    float si = 1.f / (1.f + expf(-z[0]));
    float sj = tanhf(z[1]);
    float sf = 1.f / (1.f + expf(-(z[2] + 1.f)));
    float so = 1.f / (1.f + expf(-z[3]));
    float cn = sf * c_old + si * sj;
    float hn = so * tanhf(cn);
    if (active) cb[ug * 32 + b] = cn;
    hTw[ug * 32 + b] = active ? hn : h_old;
    out[((size_t)(b * TT + pos)) * 1024 + dir * 512 + ug] = active ? hn : 0.f;
  }
}

// ---------------- CRF + pooling + final softmax ----------------
__global__ __launch_bounds__(256) void crf_final(
    const float* __restrict__ out1,
    const float* __restrict__ crf_w, const float* __restrict__ crf_b,
    const float* __restrict__ trans,
    const int* __restrict__ length,
    const float* __restrict__ lw, const float* __restrict__ lb,
    float* __restrict__ dout)
{
  __shared__ float e[TT][2];
  __shared__ float pw[TT];
  __shared__ float sv[1024];
  __shared__ float red[256];
  int b = blockIdx.x, tid = threadIdx.x;
  int lane = tid & 63, w = tid >> 6;
  const float* ob = out1 + (size_t)b * TT * 1024;
  for (int t = w; t < TT; t += 4) {
    float a0 = 0.f, a1 = 0.f;
    for (int i = 0; i < 16; ++i) {
      int d = lane + i * 64;
      float v = ob[(size_t)t * 1024 + d];
      a0 += v * crf_w[d * 2];
      a1 += v * crf_w[d * 2 + 1];
    }
    for (int off = 32; off; off >>= 1) {
      a0 += __shfl_down(a0, off);
      a1 += __shfl_down(a1, off);
    }
    if (lane == 0) { e[t][0] = a0 + crf_b[0]; e[t][1] = a1 + crf_b[1]; }
  }
  __syncthreads();
  if (tid == 0) {
    int L = length[b];
    float t00 = trans[0], t01 = trans[1], t10 = trans[2], t11 = trans[3];
    float a0 = e[0][0], a1 = e[0][1];
    {
      float m = fmaxf(a0, a1);
      float e0 = expf(a0 - m), e1 = expf(a1 - m);
      pw[0] = (L > 0) ? (e1 / (e0 + e1)) : 0.f;
    }
    for (int t = 1; t < TT; ++t) {
      if (t < L) {
        float x0 = a0 + t00, y0 = a1 + t10;
        float m0 = fmaxf(x0, y0);
        float n0 = m0 + logf(expf(x0 - m0) + expf(y0 - m0)) + e[t][0];
        float x1 = a0 + t01, y1 = a1 + t11;
        float m1 = fmaxf(x1, y1);
        float n1 = m1 + logf(expf(x1 - m1) + expf(y1 - m1)) + e[t][1];
        a0 = n0; a1 = n1;
        float m = fmaxf(a0, a1);
        float e0 = expf(a0 - m), e1 = expf(a1 - m);
        pw[t] = e1 / (e0 + e1);
      } else {
        pw[t] = 0.f;
      }
    }
  }
  __syncthreads();
  for (int i = 0; i < 4; ++i) {
    int d = tid + i * 256;
    float s = 0.f;
    for (int t = 0; t < TT; ++t) s += pw[t] * ob[(size_t)t * 1024 + d];
    sv[d] = s;
  }
  __syncthreads();
  float v[3];
  for (int c = 0; c < 3; ++c) {
    float s = 0.f;
    for (int i = 0; i < 4; ++i) {
      int d = tid + i * 256;
      s += sv[d] * lw[d * 3 + c];
    }
    red[tid] = s;
    __syncthreads();
    for (int off = 128; off; off >>= 1) {
      if (tid < off) red[tid] += red[tid + off];
      __syncthreads();
    }
    if (tid == 0) v[c] = red[0] + lb[c];
    __syncthreads();
  }
  if (tid == 0) {
    float m = fmaxf(v[0], fmaxf(v[1], v[2]));
    float e0 = expf(v[0] - m), e1 = expf(v[1] - m), e2 = expf(v[2] - m);
    float s = e0 + e1 + e2;
    dout[b * 3 + 0] = e0 / s;
    dout[b * 3 + 1] = e1 / s;
    dout[b * 3 + 2] = e2 / s;
  }
}

static void run_layer(const float* xp_fw, const float* xp_bw,
                      const float* w_fw, const float* w_bw, int din,
                      const int* len, float* out, float* hT, float* cbuf_,
                      int* bar, hipStream_t stream) {
  // zero h ping-pong + c (fallback) + barrier counters
  hipMemsetAsync(hT, 0, (65536 + 32768) * sizeof(float) + 512, stream);
  const float* a0 = xp_fw; const float* a1 = xp_bw;
  const float* a2 = w_fw;  const float* a3 = w_bw;
  int a4 = din; const int* a5 = len; float* a6 = out; float* a7 = hT;
  int* a8 = bar;
  void* args[9] = { &a0, &a1, &a2, &a3, &a4, &a5, &a6, &a7, &a8 };
  hipError_t err = hipLaunchCooperativeKernel(
      reinterpret_cast<const void*>(lstm_persist), dim3(256), dim3(256),
      args, 114688, stream);
  if (err != hipSuccess) {
    for (int t = 0; t < TT; ++t) {
      lstm_step<<<256, 256, 114688, stream>>>(xp_fw, xp_bw, w_fw, w_bw, din,
                                              len, out, hT, cbuf_, t);
    }
  }
}

extern "C" void kernel_launch(void* const* d_in, const int* in_sizes, int n_in,
                              void* d_out, int out_size, void* d_ws, size_t ws_size,
                              hipStream_t stream) {
  (void)in_sizes; (void)n_in; (void)out_size; (void)ws_size;
  const int* ids    = (const int*)d_in[0];
  const int* msk    = (const int*)d_in[1];
  const int* len    = (const int*)d_in[2];
  const float* emb  = (const float*)d_in[3];
  const float* memb = (const float*)d_in[4];
  const float* trans= (const float*)d_in[5];
  const float* w_fw0= (const float*)d_in[6];
  const float* b_fw0= (const float*)d_in[7];
  const float* w_bw0= (const float*)d_in[8];
  const float* b_bw0= (const float*)d_in[9];
  const float* w_fw1= (const float*)d_in[10];
  const float* b_fw1= (const float*)d_in[11];
  const float* w_bw1= (const float*)d_in[12];
  const float* b_bw1= (const float*)d_in[13];
  const float* crf_w= (const float*)d_in[14];
  const float* crf_b= (const float*)d_in[15];
  const float* lw   = (const float*)d_in[16];
  const float* lb   = (const float*)d_in[17];
  float* outp = (float*)d_out;

  float* ws    = (float*)d_ws;
  float* x0    = ws;
  float* xp_fw = x0 + 2867200;
  float* xp_bw = xp_fw + 16777216;
  float* out0  = xp_bw + 16777216;
  float* out1  = out0 + 8388608;
  float* hT    = out1 + 8388608;
  float* cbuf_ = hT + 65536;
  int*   bar   = (int*)(cbuf_ + 32768);

  hipFuncSetAttribute(reinterpret_cast<const void*>(lstm_persist),
                      hipFuncAttributeMaxDynamicSharedMemorySize, 114688);
  hipFuncSetAttribute(reinterpret_cast<const void*>(lstm_step),
                      hipFuncAttributeMaxDynamicSharedMemorySize, 114688);

  embed_kernel<<<8192, 256, 0, stream>>>(ids, msk, emb, memb, x0);

  dim3 gg(64, 16);
  gemm_proj<<<gg, 256, 0, stream>>>(x0, w_fw0, b_fw0, xp_fw, 8192, 350);
  gemm_proj<<<gg, 256, 0, stream>>>(x0, w_bw0, b_bw0, xp_bw, 8192, 350);

  run_layer(xp_fw, xp_bw, w_fw0, w_bw0, 350, len, out0, hT, cbuf_, bar, stream);

  gemm_proj<<<gg, 256, 0, stream>>>(out0, w_fw1, b_fw1, xp_fw, 8192, 1024);
  gemm_proj<<<gg, 256, 0, stream>>>(out0, w_bw1, b_bw1, xp_bw, 8192, 1024);

  run_layer(xp_fw, xp_bw, w_fw1, w_bw1, 1024, len, out1, hT, cbuf_, bar, stream);

  crf_final<<<32, 256, 0, stream>>>(out1, crf_w, crf_b, trans, len, lw, lb, outp);
}

// Round 3
// 21594.020 us; speedup vs baseline: 1.0151x; 1.0151x over previous
//
#include <hip/hip_runtime.h>
#include <cstdint>
#include <cstddef>

// Problem constants
#define BB 32
#define TT 256
#define HID 512
// xq layout: time-major [pos][2048 cols][32 batch]  (slab = 65536 floats)
// ws layout (floats)
//  x0     : 8192*350   = 2,867,200
//  xq_fw  : 256*65536  = 16,777,216
//  xq_bw  : 16,777,216
//  out0   : 8192*1024  = 8,388,608
//  out1   : 8,388,608
//  hT     : 2 dir * 2 buf * 512*32 = 65,536
//  cbuf   : 2 dir * 512*32         = 32,768   (fallback path only)
//  flags  : 2 dir * 128 wg * 32 ints = 8192 ints (32KB)

// ---------------- embedding + concat ----------------
__global__ __launch_bounds__(256) void embed_kernel(
    const int* __restrict__ ids, const int* __restrict__ msk,
    const float* __restrict__ emb, const float* __restrict__ memb,
    float* __restrict__ x0)
{
  int bt = blockIdx.x;            // 0..8191
  int id = ids[bt];
  int m  = msk[bt];
  const float* er = emb  + (size_t)id * 300;
  const float* mr = memb + (size_t)m * 50;
  for (int d = threadIdx.x; d < 350; d += 256) {
    x0[(size_t)bt * 350 + d] = (d < 300) ? er[d] : mr[d - 300];
  }
}

// ---- fp32 GEMM: C_t[pos][col][b] = (A[b*256+pos][:] @ W)[col] + bias[col] ----
// m-tile = 32 batches x 4 positions so each output 128B line [s][col][0..31]
// is fully written by one block (no partial-line writeback amplification).
__global__ __launch_bounds__(256) void gemm_proj_t(
    const float* __restrict__ A, const float* __restrict__ W,
    const float* __restrict__ bias, float* __restrict__ C,
    int K)
{
  const int N = 2048;
  __shared__ float As[16][128];
  __shared__ float Bs[16][128];
  int tid = threadIdx.x;
  int pos0 = blockIdx.x * 4;      // 64 blocks cover 256 positions
  int n0 = blockIdx.y * 128;
  int ty = tid >> 4, tx = tid & 15;
  float acc[8][8];
#pragma unroll
  for (int i = 0; i < 8; ++i) {
#pragma unroll
    for (int j = 0; j < 8; ++j) acc[i][j] = 0.f;
  }
  for (int k0 = 0; k0 < K; k0 += 16) {
#pragma unroll
    for (int i = 0; i < 8; ++i) {
      int e = tid + i * 256;
      int row = e >> 4, kk = e & 15;
      // tile row -> (b = row>>2, p = row&3) -> A row m = b*256 + pos0 + p
      int m = ((row >> 2) << 8) + pos0 + (row & 3);
      float v = (k0 + kk < K) ? A[(size_t)m * K + k0 + kk] : 0.f;
      As[kk][row] = v;
    }
#pragma unroll
    for (int i = 0; i < 2; ++i) {
      int e = tid + i * 256;
      int kk = e >> 5, c4 = (e & 31) << 2;
      float4 v = make_float4(0.f, 0.f, 0.f, 0.f);
      if (k0 + kk < K) v = *(const float4*)(W + (size_t)(k0 + kk) * N + n0 + c4);
      *(float4*)&Bs[kk][c4] = v;
    }
    __syncthreads();
#pragma unroll
    for (int kk = 0; kk < 16; ++kk) {
      float a[8], b[8];
      *(float4*)&a[0] = *(const float4*)&As[kk][ty * 8];
      *(float4*)&a[4] = *(const float4*)&As[kk][ty * 8 + 4];
      *(float4*)&b[0] = *(const float4*)&Bs[kk][tx * 8];
      *(float4*)&b[4] = *(const float4*)&Bs[kk][tx * 8 + 4];
#pragma unroll
      for (int i = 0; i < 8; ++i) {
#pragma unroll
        for (int j = 0; j < 8; ++j) acc[i][j] = fmaf(a[i], b[j], acc[i][j]);
      }
    }
    __syncthreads();
  }
#pragma unroll
  for (int i = 0; i < 8; ++i) {
    int r = ty * 8 + i;
    int b = r >> 2;
    int s = pos0 + (r & 3);
    float* crow = C + (size_t)s * 65536 + b;
#pragma unroll
    for (int j = 0; j < 8; ++j) {
      int col = n0 + tx * 8 + j;
      crow[(size_t)col * 32] = acc[i][j] + bias[col];
    }
  }
}

// ================= persistent bidirectional LSTM layer =================
// Cooperative, grid=256 WGs x 256 thr, 1 WG/CU (112KB dyn LDS).
// wg<128 -> fw (slab t), wg>=128 -> bw (slab 255-t, global-reversed scan:
// equivalent to reverse_sequence -> scan -> reverse_sequence since state
// is zero until batch activates at slab L-1). Each WG owns 4 hidden units.
// W slice resident in LDS; c state in registers; distributed flag barrier.
__global__ __launch_bounds__(256) void lstm_persist(
    const float* __restrict__ xq_fw, const float* __restrict__ xq_bw,
    const float* __restrict__ w_fw, const float* __restrict__ w_bw,
    int din,
    const int* __restrict__ length,
    float* __restrict__ out,      // (B,T,1024)
    float* __restrict__ hT,       // [dir][2][512][32]
    int* __restrict__ flags)      // [dir][128][32]
{
  extern __shared__ float smem[];
  float* Wl = smem;              // [512][16]  32KB
  float* hs = smem + 512 * 16;   // [512][32]  64KB
  float* zs = hs + 512 * 32;     // [8][512]   16KB
  int tid = threadIdx.x;
  int wg = blockIdx.x;
  int dir = wg >> 7;
  int u0 = (wg & 127) << 2;
  const float* Wm = dir ? w_bw : w_fw;
  const float* xq = dir ? xq_bw : xq_fw;
  float* hbase = hT + (size_t)dir * 32768;
  int* dirflags = flags + dir * 4096;
  int* myflag = dirflags + (wg & 127) * 32;

  // ---- load recurrent-weight slice ONCE ----
  {
    const float* wbase = Wm + (size_t)din * 2048 + u0;
#pragma unroll
    for (int kk = 0; kk < 2; ++kk) {
      int k = tid * 2 + kk;
      const float* wr = wbase + (size_t)k * 2048;
#pragma unroll
      for (int q = 0; q < 4; ++q) {
        *(float4*)&Wl[k * 16 + q * 4] = *(const float4*)(wr + q * 512);
      }
    }
  }

  // compute-phase constants
  int ks = tid >> 5;
  int tile = tid & 31;
  int c0 = (tile & 3) << 2;
  int b0 = (tile >> 2) << 2;
  int kbeg = ks << 6;
  // finalize-phase constants (tid < 128)
  int fu = tid >> 5;         // 0..3
  int fb = tid & 31;         // batch
  int L = length[fb & 31];
  float creg = 0.f;

  for (int t = 0; t < TT; ++t) {
    int sl = dir ? (TT - 1 - t) : t;   // slab index this step
    const float* hTr = hbase + (size_t)(t & 1) * 16384;
    float* hTw = hbase + (size_t)((t & 1) ^ 1) * 16384;

    // prefetch x-projection values for this step (coalesced, time-major)
    float xv0 = 0.f, xv1 = 0.f, xv2 = 0.f, xv3 = 0.f;
    if (tid < 128) {
      const float* xr = xq + (size_t)sl * 65536 + (u0 + fu) * 32 + fb;
      xv0 = xr[0];
      xv1 = xr[16384];
      xv2 = xr[32768];
      xv3 = xr[49152];
    }

    // stage previous h : [512][32] linear
#pragma unroll
    for (int i = 0; i < 16; ++i) {
      int e = (tid + i * 256) * 4;
      *(float4*)&hs[e] = *(const float4*)&hTr[e];
    }
    __syncthreads();

    // partial z: thread = (ks, 4 cols, 4 batches), k-split 8
    float acc[4][4];
#pragma unroll
    for (int i = 0; i < 4; ++i) {
#pragma unroll
      for (int j = 0; j < 4; ++j) acc[i][j] = 0.f;
    }
    for (int k = kbeg; k < kbeg + 64; ++k) {
      float4 w4 = *(const float4*)&Wl[k * 16 + c0];
      float4 h4 = *(const float4*)&hs[k * 32 + b0];
      acc[0][0] = fmaf(w4.x, h4.x, acc[0][0]);
      acc[0][1] = fmaf(w4.x, h4.y, acc[0][1]);
      acc[0][2] = fmaf(w4.x, h4.z, acc[0][2]);
      acc[0][3] = fmaf(w4.x, h4.w, acc[0][3]);
      acc[1][0] = fmaf(w4.y, h4.x, acc[1][0]);
      acc[1][1] = fmaf(w4.y, h4.y, acc[1][1]);
      acc[1][2] = fmaf(w4.y, h4.z, acc[1][2]);
      acc[1][3] = fmaf(w4.y, h4.w, acc[1][3]);
      acc[2][0] = fmaf(w4.z, h4.x, acc[2][0]);
      acc[2][1] = fmaf(w4.z, h4.y, acc[2][1]);
      acc[2][2] = fmaf(w4.z, h4.z, acc[2][2]);
      acc[2][3] = fmaf(w4.z, h4.w, acc[2][3]);
      acc[3][0] = fmaf(w4.w, h4.x, acc[3][0]);
      acc[3][1] = fmaf(w4.w, h4.y, acc[3][1]);
      acc[3][2] = fmaf(w4.w, h4.z, acc[3][2]);
      acc[3][3] = fmaf(w4.w, h4.w, acc[3][3]);
    }
#pragma unroll
    for (int ci = 0; ci < 4; ++ci) {
      *(float4*)&zs[ks * 512 + (c0 + ci) * 32 + b0] =
          make_float4(acc[ci][0], acc[ci][1], acc[ci][2], acc[ci][3]);
    }
    __syncthreads();

    if (tid < 128) {
      bool active = sl < L;
      int ug = u0 + fu;
      float z0 = xv0, z1 = xv1, z2 = xv2, z3 = xv3;
#pragma unroll
      for (int p = 0; p < 8; ++p) {
        z0 += zs[p * 512 + (0 * 4 + fu) * 32 + fb];
        z1 += zs[p * 512 + (1 * 4 + fu) * 32 + fb];
        z2 += zs[p * 512 + (2 * 4 + fu) * 32 + fb];
        z3 += zs[p * 512 + (3 * 4 + fu) * 32 + fb];
      }
      float h_old = hs[ug * 32 + fb];
      float si = 1.f / (1.f + expf(-z0));
      float sj = tanhf(z1);
      float sf = 1.f / (1.f + expf(-(z2 + 1.f)));
      float so = 1.f / (1.f + expf(-z3));
      float cn = sf * creg + si * sj;
      float hn = so * tanhf(cn);
      if (active) creg = cn;
      hTw[ug * 32 + fb] = active ? hn : h_old;
      out[((size_t)(fb * TT + sl)) * 1024 + dir * 512 + ug] = active ? hn : 0.f;
    }

    // -------- distributed flag barrier (per direction, 128 WGs) --------
    __threadfence();
    __syncthreads();
    if (tid == 0) {
      __hip_atomic_store(myflag, t + 1, __ATOMIC_RELEASE,
                         __HIP_MEMORY_SCOPE_AGENT);
    }
    if (tid < 128) {
      int* f = dirflags + tid * 32;
      while (__hip_atomic_load(f, __ATOMIC_ACQUIRE,
                               __HIP_MEMORY_SCOPE_AGENT) < t + 1) {
        __builtin_amdgcn_s_sleep(1);
      }
    }
    __syncthreads();
  }
}

// ---------------- fallback: one LSTM timestep (per-launch) --------
__global__ __launch_bounds__(256) void lstm_step(
    const float* __restrict__ xq_fw, const float* __restrict__ xq_bw,
    const float* __restrict__ w_fw, const float* __restrict__ w_bw,
    int din,
    const int* __restrict__ length,
    float* __restrict__ out,
    float* __restrict__ hT,
    float* __restrict__ cbuf,
    int t)
{
  extern __shared__ float smem[];
  float* Wl = smem;
  float* hs = smem + 512 * 16;
  float* zs = hs + 512 * 32;
  int tid = threadIdx.x;
  int wg = blockIdx.x;
  int dir = wg >> 7;
  int u0 = (wg & 127) << 2;
  const float* Wm = dir ? w_bw : w_fw;
  const float* xq = dir ? xq_bw : xq_fw;
  const float* hTr = hT + (size_t)dir * 32768 + (size_t)(t & 1) * 16384;
  float* hTw = hT + (size_t)dir * 32768 + (size_t)((t & 1) ^ 1) * 16384;
  float* cb = cbuf + (size_t)dir * 16384;
  int sl = dir ? (TT - 1 - t) : t;
  {
    const float* wbase = Wm + (size_t)din * 2048 + u0;
#pragma unroll
    for (int kk = 0; kk < 2; ++kk) {
      int k = tid * 2 + kk;
      const float* wr = wbase + (size_t)k * 2048;
#pragma unroll
      for (int q = 0; q < 4; ++q) {
        *(float4*)&Wl[k * 16 + q * 4] = *(const float4*)(wr + q * 512);
      }
    }
  }
#pragma unroll
  for (int i = 0; i < 16; ++i) {
    int e = (tid + i * 256) * 4;
    *(float4*)&hs[e] = *(const float4*)&hTr[e];
  }
  __syncthreads();
  int ks = tid >> 5;
  int tile = tid & 31;
  int c0 = (tile & 3) << 2;
  int b0 = (tile >> 2) << 2;
  float acc[4][4];
#pragma unroll
  for (int i = 0; i < 4; ++i) {
#pragma unroll
    for (int j = 0; j < 4; ++j) acc[i][j] = 0.f;
  }
  int kbeg = ks << 6;
  for (int k = kbeg; k < kbeg + 64; ++k) {
    float4 w4 = *(const float4*)&Wl[k * 16 + c0];
    float4 h4 = *(const float4*)&hs[k * 32 + b0];
    acc[0][0] = fmaf(w4.x, h4.x, acc[0][0]);
    acc[0][1] = fmaf(w4.x, h4.y, acc[0][1]);
    acc[0][2] = fmaf(w4.x, h4.z, acc[0][2]);
    acc[0][3] = fmaf(w4.x, h4.w, acc[0][3]);
    acc[1][0] = fmaf(w4.y, h4.x, acc[1][0]);
    acc[1][1] = fmaf(w4.y, h4.y, acc[1][1]);
    acc[1][2] = fmaf(w4.y, h4.z, acc[1][2]);
    acc[1][3] = fmaf(w4.y, h4.w, acc[1][3]);
    acc[2][0] = fmaf(w4.z, h4.x, acc[2][0]);
    acc[2][1] = fmaf(w4.z, h4.y, acc[2][1]);
    acc[2][2] = fmaf(w4.z, h4.z, acc[2][2]);
    acc[2][3] = fmaf(w4.z, h4.w, acc[2][3]);
    acc[3][0] = fmaf(w4.w, h4.x, acc[3][0]);
    acc[3][1] = fmaf(w4.w, h4.y, acc[3][1]);
    acc[3][2] = fmaf(w4.w, h4.z, acc[3][2]);
    acc[3][3] = fmaf(w4.w, h4.w, acc[3][3]);
  }
#pragma unroll
  for (int ci = 0; ci < 4; ++ci) {
    *(float4*)&zs[ks * 512 + (c0 + ci) * 32 + b0] =
        make_float4(acc[ci][0], acc[ci][1], acc[ci][2], acc[ci][3]);
  }
  __syncthreads();
  if (tid < 128) {
    int u = tid >> 5;
    int b = tid & 31;
    int L = length[b];
    bool active = sl < L;
    int ug = u0 + u;
    const float* xr = xq + (size_t)sl * 65536 + ug * 32 + b;
    float z[4];
#pragma unroll
    for (int q = 0; q < 4; ++q) {
      float s = xr[(size_t)q * 16384];
#pragma unroll
      for (int p = 0; p < 8; ++p) s += zs[p * 512 + (q * 4 + u) * 32 + b];
      z[q] = s;
    }
    float c_old = cb[ug * 32 + b];
    float h_old = hs[ug * 32 + b];
    float si = 1.f / (1.f + expf(-z[0]));
    float sj = tanhf(z[1]);
    float sf = 1.f / (1.f + expf(-(z[2] + 1.f)));
    float so = 1.f / (1.f + expf(-z[3]));
    float cn = sf * c_old + si * sj;
    float hn = so * tanhf(cn);
    if (active) cb[ug * 32 + b] = cn;
    hTw[ug * 32 + b] = active ? hn : h_old;
    out[((size_t)(b * TT + sl)) * 1024 + dir * 512 + ug] = active ? hn : 0.f;
  }
}

// ---------------- CRF + pooling + final softmax ----------------
__global__ __launch_bounds__(256) void crf_final(
    const float* __restrict__ out1,
    const float* __restrict__ crf_w, const float* __restrict__ crf_b,
    const float* __restrict__ trans,
    const int* __restrict__ length,
    const float* __restrict__ lw, const float* __restrict__ lb,
    float* __restrict__ dout)
{
  __shared__ float e[TT][2];
  __shared__ float pw[TT];
  __shared__ float sv[1024];
  __shared__ float red[256];
  int b = blockIdx.x, tid = threadIdx.x;
  int lane = tid & 63, w = tid >> 6;
  const float* ob = out1 + (size_t)b * TT * 1024;
  for (int t = w; t < TT; t += 4) {
    float a0 = 0.f, a1 = 0.f;
    for (int i = 0; i < 16; ++i) {
      int d = lane + i * 64;
      float v = ob[(size_t)t * 1024 + d];
      a0 += v * crf_w[d * 2];
      a1 += v * crf_w[d * 2 + 1];
    }
    for (int off = 32; off; off >>= 1) {
      a0 += __shfl_down(a0, off);
      a1 += __shfl_down(a1, off);
    }
    if (lane == 0) { e[t][0] = a0 + crf_b[0]; e[t][1] = a1 + crf_b[1]; }
  }
  __syncthreads();
  if (tid == 0) {
    int L = length[b];
    float t00 = trans[0], t01 = trans[1], t10 = trans[2], t11 = trans[3];
    float a0 = e[0][0], a1 = e[0][1];
    {
      float m = fmaxf(a0, a1);
      float e0 = expf(a0 - m), e1 = expf(a1 - m);
      pw[0] = (L > 0) ? (e1 / (e0 + e1)) : 0.f;
    }
    for (int t = 1; t < TT; ++t) {
      if (t < L) {
        float x0 = a0 + t00, y0 = a1 + t10;
        float m0 = fmaxf(x0, y0);
        float n0 = m0 + logf(expf(x0 - m0) + expf(y0 - m0)) + e[t][0];
        float x1 = a0 + t01, y1 = a1 + t11;
        float m1 = fmaxf(x1, y1);
        float n1 = m1 + logf(expf(x1 - m1) + expf(y1 - m1)) + e[t][1];
        a0 = n0; a1 = n1;
        float m = fmaxf(a0, a1);
        float e0 = expf(a0 - m), e1 = expf(a1 - m);
        pw[t] = e1 / (e0 + e1);
      } else {
        pw[t] = 0.f;
      }
    }
  }
  __syncthreads();
  for (int i = 0; i < 4; ++i) {
    int d = tid + i * 256;
    float s = 0.f;
    for (int t = 0; t < TT; ++t) s += pw[t] * ob[(size_t)t * 1024 + d];
    sv[d] = s;
  }
  __syncthreads();
  float v[3];
  for (int c = 0; c < 3; ++c) {
    float s = 0.f;
    for (int i = 0; i < 4; ++i) {
      int d = tid + i * 256;
      s += sv[d] * lw[d * 3 + c];
    }
    red[tid] = s;
    __syncthreads();
    for (int off = 128; off; off >>= 1) {
      if (tid < off) red[tid] += red[tid + off];
      __syncthreads();
    }
    if (tid == 0) v[c] = red[0] + lb[c];
    __syncthreads();
  }
  if (tid == 0) {
    float m = fmaxf(v[0], fmaxf(v[1], v[2]));
    float e0 = expf(v[0] - m), e1 = expf(v[1] - m), e2 = expf(v[2] - m);
    float s = e0 + e1 + e2;
    dout[b * 3 + 0] = e0 / s;
    dout[b * 3 + 1] = e1 / s;
    dout[b * 3 + 2] = e2 / s;
  }
}

static void run_layer(const float* xq_fw, const float* xq_bw,
                      const float* w_fw, const float* w_bw, int din,
                      const int* len, float* out, float* hT, float* cbuf_,
                      int* flags, hipStream_t stream) {
  // zero h ping-pong + c (fallback) + flags
  hipMemsetAsync(hT, 0, (65536 + 32768) * sizeof(float) + 8192 * sizeof(int),
                 stream);
  const float* a0 = xq_fw; const float* a1 = xq_bw;
  const float* a2 = w_fw;  const float* a3 = w_bw;
  int a4 = din; const int* a5 = len; float* a6 = out; float* a7 = hT;
  int* a8 = flags;
  void* args[9] = { &a0, &a1, &a2, &a3, &a4, &a5, &a6, &a7, &a8 };
  hipError_t err = hipLaunchCooperativeKernel(
      reinterpret_cast<const void*>(lstm_persist), dim3(256), dim3(256),
      args, 114688, stream);
  if (err != hipSuccess) {
    for (int t = 0; t < TT; ++t) {
      lstm_step<<<256, 256, 114688, stream>>>(xq_fw, xq_bw, w_fw, w_bw, din,
                                              len, out, hT, cbuf_, t);
    }
  }
}

extern "C" void kernel_launch(void* const* d_in, const int* in_sizes, int n_in,
                              void* d_out, int out_size, void* d_ws, size_t ws_size,
                              hipStream_t stream) {
  (void)in_sizes; (void)n_in; (void)out_size; (void)ws_size;
  const int* ids    = (const int*)d_in[0];
  const int* msk    = (const int*)d_in[1];
  const int* len    = (const int*)d_in[2];
  const float* emb  = (const float*)d_in[3];
  const float* memb = (const float*)d_in[4];
  const float* trans= (const float*)d_in[5];
  const float* w_fw0= (const float*)d_in[6];
  const float* b_fw0= (const float*)d_in[7];
  const float* w_bw0= (const float*)d_in[8];
  const float* b_bw0= (const float*)d_in[9];
  const float* w_fw1= (const float*)d_in[10];
  const float* b_fw1= (const float*)d_in[11];
  const float* w_bw1= (const float*)d_in[12];
  const float* b_bw1= (const float*)d_in[13];
  const float* crf_w= (const float*)d_in[14];
  const float* crf_b= (const float*)d_in[15];
  const float* lw   = (const float*)d_in[16];
  const float* lb   = (const float*)d_in[17];
  float* outp = (float*)d_out;

  float* ws    = (float*)d_ws;
  float* x0    = ws;
  float* xq_fw = x0 + 2867200;
  float* xq_bw = xq_fw + 16777216;
  float* out0  = xq_bw + 16777216;
  float* out1  = out0 + 8388608;
  float* hT    = out1 + 8388608;
  float* cbuf_ = hT + 65536;
  int*   flags = (int*)(cbuf_ + 32768);

  hipFuncSetAttribute(reinterpret_cast<const void*>(lstm_persist),
                      hipFuncAttributeMaxDynamicSharedMemorySize, 114688);
  hipFuncSetAttribute(reinterpret_cast<const void*>(lstm_step),
                      hipFuncAttributeMaxDynamicSharedMemorySize, 114688);

  embed_kernel<<<8192, 256, 0, stream>>>(ids, msk, emb, memb, x0);

  dim3 gg(64, 16);
  gemm_proj_t<<<gg, 256, 0, stream>>>(x0, w_fw0, b_fw0, xq_fw, 350);
  gemm_proj_t<<<gg, 256, 0, stream>>>(x0, w_bw0, b_bw0, xq_bw, 350);

  run_layer(xq_fw, xq_bw, w_fw0, w_bw0, 350, len, out0, hT, cbuf_, flags, stream);

  gemm_proj_t<<<gg, 256, 0, stream>>>(out0, w_fw1, b_fw1, xq_fw, 1024);
  gemm_proj_t<<<gg, 256, 0, stream>>>(out0, w_bw1, b_bw1, xq_bw, 1024);

  run_layer(xq_fw, xq_bw, w_fw1, w_bw1, 1024, len, out1, hT, cbuf_, flags, stream);

  crf_final<<<32, 256, 0, stream>>>(out1, crf_w, crf_b, trans, len, lw, lb, outp);
}

// Round 4
// 4650.174 us; speedup vs baseline: 4.7138x; 4.6437x over previous
//
#include <hip/hip_runtime.h>
#include <cstdint>
#include <cstddef>

// Problem constants
#define BB 32
#define TT 256
#define HID 512
// xq layout: time-major [pos][2048 cols][32 batch]  (slab = 65536 floats)
// ws layout (floats)
//  x0     : 8192*350   = 2,867,200
//  xq_fw  : 256*65536  = 16,777,216
//  xq_bw  : 16,777,216
//  out0   : 8192*1024  = 8,388,608
//  out1   : 8,388,608
//  hT     : 2 dir * 2 buf * 512*32 = 65,536
//  cbuf   : 2 dir * 512*32         = 32,768   (fallback path only)
//  flags  : 2 dir * 128 wg * 32 ints = 8192 ints (32KB)

// device-coherent (agent-scope) 16B/4B accesses: bypass L1+L2, hit the
// coherence point directly -> no fences / L2 writebacks / invalidates needed.
__device__ __forceinline__ void stg4_cohere(float* p, float4 v) {
  asm volatile("global_store_dwordx4 %0, %1, off sc0 sc1"
               :: "v"(p), "v"(v) : "memory");
}
__device__ __forceinline__ void stg1_cohere(float* p, float v) {
  asm volatile("global_store_dword %0, %1, off sc0 sc1"
               :: "v"(p), "v"(v) : "memory");
}
__device__ __forceinline__ void ldg4_cohere_issue(float4& d, const float* p) {
  asm volatile("global_load_dwordx4 %0, %1, off sc0 sc1"
               : "=v"(d) : "v"(p) : "memory");
}
__device__ __forceinline__ void wait_vm0() {
  asm volatile("s_waitcnt vmcnt(0)" ::: "memory");
  __builtin_amdgcn_sched_barrier(0);
}

// ---------------- embedding + concat ----------------
__global__ __launch_bounds__(256) void embed_kernel(
    const int* __restrict__ ids, const int* __restrict__ msk,
    const float* __restrict__ emb, const float* __restrict__ memb,
    float* __restrict__ x0)
{
  int bt = blockIdx.x;            // 0..8191
  int id = ids[bt];
  int m  = msk[bt];
  const float* er = emb  + (size_t)id * 300;
  const float* mr = memb + (size_t)m * 50;
  for (int d = threadIdx.x; d < 350; d += 256) {
    x0[(size_t)bt * 350 + d] = (d < 300) ? er[d] : mr[d - 300];
  }
}

// ---- fp32 GEMM: C_t[pos][col][b] = (A[b*256+pos][:] @ W)[col] + bias[col] ----
__global__ __launch_bounds__(256) void gemm_proj_t(
    const float* __restrict__ A, const float* __restrict__ W,
    const float* __restrict__ bias, float* __restrict__ C,
    int K)
{
  const int N = 2048;
  __shared__ float As[16][128];
  __shared__ float Bs[16][128];
  int tid = threadIdx.x;
  int pos0 = blockIdx.x * 4;      // 64 blocks cover 256 positions
  int n0 = blockIdx.y * 128;
  int ty = tid >> 4, tx = tid & 15;
  float acc[8][8];
#pragma unroll
  for (int i = 0; i < 8; ++i) {
#pragma unroll
    for (int j = 0; j < 8; ++j) acc[i][j] = 0.f;
  }
  for (int k0 = 0; k0 < K; k0 += 16) {
#pragma unroll
    for (int i = 0; i < 8; ++i) {
      int e = tid + i * 256;
      int row = e >> 4, kk = e & 15;
      int m = ((row >> 2) << 8) + pos0 + (row & 3);
      float v = (k0 + kk < K) ? A[(size_t)m * K + k0 + kk] : 0.f;
      As[kk][row] = v;
    }
#pragma unroll
    for (int i = 0; i < 2; ++i) {
      int e = tid + i * 256;
      int kk = e >> 5, c4 = (e & 31) << 2;
      float4 v = make_float4(0.f, 0.f, 0.f, 0.f);
      if (k0 + kk < K) v = *(const float4*)(W + (size_t)(k0 + kk) * N + n0 + c4);
      *(float4*)&Bs[kk][c4] = v;
    }
    __syncthreads();
#pragma unroll
    for (int kk = 0; kk < 16; ++kk) {
      float a[8], b[8];
      *(float4*)&a[0] = *(const float4*)&As[kk][ty * 8];
      *(float4*)&a[4] = *(const float4*)&As[kk][ty * 8 + 4];
      *(float4*)&b[0] = *(const float4*)&Bs[kk][tx * 8];
      *(float4*)&b[4] = *(const float4*)&Bs[kk][tx * 8 + 4];
#pragma unroll
      for (int i = 0; i < 8; ++i) {
#pragma unroll
        for (int j = 0; j < 8; ++j) acc[i][j] = fmaf(a[i], b[j], acc[i][j]);
      }
    }
    __syncthreads();
  }
#pragma unroll
  for (int i = 0; i < 8; ++i) {
    int r = ty * 8 + i;
    int b = r >> 2;
    int s = pos0 + (r & 3);
    float* crow = C + (size_t)s * 65536 + b;
#pragma unroll
    for (int j = 0; j < 8; ++j) {
      int col = n0 + tx * 8 + j;
      crow[(size_t)col * 32] = acc[i][j] + bias[col];
    }
  }
}

// ================= persistent bidirectional LSTM layer =================
// Cooperative, grid=256 WGs x 256 thr, 1 WG/CU (112KB dyn LDS).
// Cross-WG state (hT, flags) moves ONLY via sc0sc1 coherent ops + relaxed
// agent atomics: no fences, no L2 writeback/invalidate storms.
__global__ __launch_bounds__(256) void lstm_persist(
    const float* __restrict__ xq_fw, const float* __restrict__ xq_bw,
    const float* __restrict__ w_fw, const float* __restrict__ w_bw,
    int din,
    const int* __restrict__ length,
    float* __restrict__ out,      // (B,T,1024)
    float* __restrict__ hT,       // [dir][2][512][32]
    int* __restrict__ flags)      // [dir][128][32]
{
  extern __shared__ float smem[];
  float* Wl = smem;              // [512][16]  32KB
  float* hs = smem + 512 * 16;   // [512][32]  64KB
  float* zs = hs + 512 * 32;     // [8][512]   16KB
  int tid = threadIdx.x;
  int wg = blockIdx.x;
  int dir = wg >> 7;
  int u0 = (wg & 127) << 2;
  const float* Wm = dir ? w_bw : w_fw;
  const float* xq = dir ? xq_bw : xq_fw;
  float* hbase = hT + (size_t)dir * 32768;
  int* dirflags = flags + dir * 4096;
  int* myflag = dirflags + (wg & 127) * 32;

  // ---- load recurrent-weight slice ONCE ----
  {
    const float* wbase = Wm + (size_t)din * 2048 + u0;
#pragma unroll
    for (int kk = 0; kk < 2; ++kk) {
      int k = tid * 2 + kk;
      const float* wr = wbase + (size_t)k * 2048;
#pragma unroll
      for (int q = 0; q < 4; ++q) {
        *(float4*)&Wl[k * 16 + q * 4] = *(const float4*)(wr + q * 512);
      }
    }
  }

  // compute-phase constants
  int ks = tid >> 5;
  int tile = tid & 31;
  int c0 = (tile & 3) << 2;
  int b0 = (tile >> 2) << 2;
  int kbeg = ks << 6;
  // finalize-phase constants (tid < 128)
  int fu = tid >> 5;         // 0..3
  int fb = tid & 31;         // batch
  int L = length[fb & 31];
  float creg = 0.f;

  for (int t = 0; t < TT; ++t) {
    int sl = dir ? (TT - 1 - t) : t;   // slab index this step
    const float* hTr = hbase + (size_t)(t & 1) * 16384;
    float* hTw = hbase + (size_t)((t & 1) ^ 1) * 16384;

    // prefetch x-projection values for this step (coalesced, time-major)
    float xv0 = 0.f, xv1 = 0.f, xv2 = 0.f, xv3 = 0.f;
    if (tid < 128) {
      const float* xr = xq + (size_t)sl * 65536 + (u0 + fu) * 32 + fb;
      xv0 = xr[0];
      xv1 = xr[16384];
      xv2 = xr[32768];
      xv3 = xr[49152];
    }

    // stage previous h via coherent loads: 2 batches of 8x dwordx4
    {
      float4 r0, r1, r2, r3, r4, r5, r6, r7;
      int e0 = tid * 4;
      ldg4_cohere_issue(r0, hTr + e0 + 0 * 1024);
      ldg4_cohere_issue(r1, hTr + e0 + 1 * 1024);
      ldg4_cohere_issue(r2, hTr + e0 + 2 * 1024);
      ldg4_cohere_issue(r3, hTr + e0 + 3 * 1024);
      ldg4_cohere_issue(r4, hTr + e0 + 4 * 1024);
      ldg4_cohere_issue(r5, hTr + e0 + 5 * 1024);
      ldg4_cohere_issue(r6, hTr + e0 + 6 * 1024);
      ldg4_cohere_issue(r7, hTr + e0 + 7 * 1024);
      wait_vm0();
      *(float4*)&hs[e0 + 0 * 1024] = r0;
      *(float4*)&hs[e0 + 1 * 1024] = r1;
      *(float4*)&hs[e0 + 2 * 1024] = r2;
      *(float4*)&hs[e0 + 3 * 1024] = r3;
      *(float4*)&hs[e0 + 4 * 1024] = r4;
      *(float4*)&hs[e0 + 5 * 1024] = r5;
      *(float4*)&hs[e0 + 6 * 1024] = r6;
      *(float4*)&hs[e0 + 7 * 1024] = r7;
      ldg4_cohere_issue(r0, hTr + e0 + 8 * 1024);
      ldg4_cohere_issue(r1, hTr + e0 + 9 * 1024);
      ldg4_cohere_issue(r2, hTr + e0 + 10 * 1024);
      ldg4_cohere_issue(r3, hTr + e0 + 11 * 1024);
      ldg4_cohere_issue(r4, hTr + e0 + 12 * 1024);
      ldg4_cohere_issue(r5, hTr + e0 + 13 * 1024);
      ldg4_cohere_issue(r6, hTr + e0 + 14 * 1024);
      ldg4_cohere_issue(r7, hTr + e0 + 15 * 1024);
      wait_vm0();
      *(float4*)&hs[e0 + 8 * 1024] = r0;
      *(float4*)&hs[e0 + 9 * 1024] = r1;
      *(float4*)&hs[e0 + 10 * 1024] = r2;
      *(float4*)&hs[e0 + 11 * 1024] = r3;
      *(float4*)&hs[e0 + 12 * 1024] = r4;
      *(float4*)&hs[e0 + 13 * 1024] = r5;
      *(float4*)&hs[e0 + 14 * 1024] = r6;
      *(float4*)&hs[e0 + 15 * 1024] = r7;
    }
    __syncthreads();

    // partial z: thread = (ks, 4 cols, 4 batches), k-split 8
    float acc[4][4];
#pragma unroll
    for (int i = 0; i < 4; ++i) {
#pragma unroll
      for (int j = 0; j < 4; ++j) acc[i][j] = 0.f;
    }
    for (int k = kbeg; k < kbeg + 64; ++k) {
      float4 w4 = *(const float4*)&Wl[k * 16 + c0];
      float4 h4 = *(const float4*)&hs[k * 32 + b0];
      acc[0][0] = fmaf(w4.x, h4.x, acc[0][0]);
      acc[0][1] = fmaf(w4.x, h4.y, acc[0][1]);
      acc[0][2] = fmaf(w4.x, h4.z, acc[0][2]);
      acc[0][3] = fmaf(w4.x, h4.w, acc[0][3]);
      acc[1][0] = fmaf(w4.y, h4.x, acc[1][0]);
      acc[1][1] = fmaf(w4.y, h4.y, acc[1][1]);
      acc[1][2] = fmaf(w4.y, h4.z, acc[1][2]);
      acc[1][3] = fmaf(w4.y, h4.w, acc[1][3]);
      acc[2][0] = fmaf(w4.z, h4.x, acc[2][0]);
      acc[2][1] = fmaf(w4.z, h4.y, acc[2][1]);
      acc[2][2] = fmaf(w4.z, h4.z, acc[2][2]);
      acc[2][3] = fmaf(w4.z, h4.w, acc[2][3]);
      acc[3][0] = fmaf(w4.w, h4.x, acc[3][0]);
      acc[3][1] = fmaf(w4.w, h4.y, acc[3][1]);
      acc[3][2] = fmaf(w4.w, h4.z, acc[3][2]);
      acc[3][3] = fmaf(w4.w, h4.w, acc[3][3]);
    }
#pragma unroll
    for (int ci = 0; ci < 4; ++ci) {
      *(float4*)&zs[ks * 512 + (c0 + ci) * 32 + b0] =
          make_float4(acc[ci][0], acc[ci][1], acc[ci][2], acc[ci][3]);
    }
    __syncthreads();

    if (tid < 128) {
      bool active = sl < L;
      int ug = u0 + fu;
      float z0 = xv0, z1 = xv1, z2 = xv2, z3 = xv3;
#pragma unroll
      for (int p = 0; p < 8; ++p) {
        z0 += zs[p * 512 + (0 * 4 + fu) * 32 + fb];
        z1 += zs[p * 512 + (1 * 4 + fu) * 32 + fb];
        z2 += zs[p * 512 + (2 * 4 + fu) * 32 + fb];
        z3 += zs[p * 512 + (3 * 4 + fu) * 32 + fb];
      }
      float h_old = hs[ug * 32 + fb];
      float si = 1.f / (1.f + expf(-z0));
      float sj = tanhf(z1);
      float sf = 1.f / (1.f + expf(-(z2 + 1.f)));
      float so = 1.f / (1.f + expf(-z3));
      float cn = sf * creg + si * sj;
      float hn = so * tanhf(cn);
      if (active) creg = cn;
      stg1_cohere(&hTw[ug * 32 + fb], active ? hn : h_old);
      out[((size_t)(fb * TT + sl)) * 1024 + dir * 512 + ug] = active ? hn : 0.f;
    }

    // -------- flag barrier: no fences, coherent ops only --------
    wait_vm0();                      // per-wave: h-stores at coherence point
    __syncthreads();                 // all waves done
    if (tid == 0) {
      __hip_atomic_store(myflag, t + 1, __ATOMIC_RELAXED,
                         __HIP_MEMORY_SCOPE_AGENT);
    }
    if (tid < 128) {
      int* f = dirflags + tid * 32;
      while (__hip_atomic_load(f, __ATOMIC_RELAXED,
                               __HIP_MEMORY_SCOPE_AGENT) < t + 1) {
        __builtin_amdgcn_s_sleep(1);
      }
    }
    __syncthreads();
  }
}

// ---------------- fallback: one LSTM timestep (per-launch) --------
__global__ __launch_bounds__(256) void lstm_step(
    const float* __restrict__ xq_fw, const float* __restrict__ xq_bw,
    const float* __restrict__ w_fw, const float* __restrict__ w_bw,
    int din,
    const int* __restrict__ length,
    float* __restrict__ out,
    float* __restrict__ hT,
    float* __restrict__ cbuf,
    int t)
{
  extern __shared__ float smem[];
  float* Wl = smem;
  float* hs = smem + 512 * 16;
  float* zs = hs + 512 * 32;
  int tid = threadIdx.x;
  int wg = blockIdx.x;
  int dir = wg >> 7;
  int u0 = (wg & 127) << 2;
  const float* Wm = dir ? w_bw : w_fw;
  const float* xq = dir ? xq_bw : xq_fw;
  const float* hTr = hT + (size_t)dir * 32768 + (size_t)(t & 1) * 16384;
  float* hTw = hT + (size_t)dir * 32768 + (size_t)((t & 1) ^ 1) * 16384;
  float* cb = cbuf + (size_t)dir * 16384;
  int sl = dir ? (TT - 1 - t) : t;
  {
    const float* wbase = Wm + (size_t)din * 2048 + u0;
#pragma unroll
    for (int kk = 0; kk < 2; ++kk) {
      int k = tid * 2 + kk;
      const float* wr = wbase + (size_t)k * 2048;
#pragma unroll
      for (int q = 0; q < 4; ++q) {
        *(float4*)&Wl[k * 16 + q * 4] = *(const float4*)(wr + q * 512);
      }
    }
  }
#pragma unroll
  for (int i = 0; i < 16; ++i) {
    int e = (tid + i * 256) * 4;
    *(float4*)&hs[e] = *(const float4*)&hTr[e];
  }
  __syncthreads();
  int ks = tid >> 5;
  int tile = tid & 31;
  int c0 = (tile & 3) << 2;
  int b0 = (tile >> 2) << 2;
  float acc[4][4];
#pragma unroll
  for (int i = 0; i < 4; ++i) {
#pragma unroll
    for (int j = 0; j < 4; ++j) acc[i][j] = 0.f;
  }
  int kbeg = ks << 6;
  for (int k = kbeg; k < kbeg + 64; ++k) {
    float4 w4 = *(const float4*)&Wl[k * 16 + c0];
    float4 h4 = *(const float4*)&hs[k * 32 + b0];
    acc[0][0] = fmaf(w4.x, h4.x, acc[0][0]);
    acc[0][1] = fmaf(w4.x, h4.y, acc[0][1]);
    acc[0][2] = fmaf(w4.x, h4.z, acc[0][2]);
    acc[0][3] = fmaf(w4.x, h4.w, acc[0][3]);
    acc[1][0] = fmaf(w4.y, h4.x, acc[1][0]);
    acc[1][1] = fmaf(w4.y, h4.y, acc[1][1]);
    acc[1][2] = fmaf(w4.y, h4.z, acc[1][2]);
    acc[1][3] = fmaf(w4.y, h4.w, acc[1][3]);
    acc[2][0] = fmaf(w4.z, h4.x, acc[2][0]);
    acc[2][1] = fmaf(w4.z, h4.y, acc[2][1]);
    acc[2][2] = fmaf(w4.z, h4.z, acc[2][2]);
    acc[2][3] = fmaf(w4.z, h4.w, acc[2][3]);
    acc[3][0] = fmaf(w4.w, h4.x, acc[3][0]);
    acc[3][1] = fmaf(w4.w, h4.y, acc[3][1]);
    acc[3][2] = fmaf(w4.w, h4.z, acc[3][2]);
    acc[3][3] = fmaf(w4.w, h4.w, acc[3][3]);
  }
#pragma unroll
  for (int ci = 0; ci < 4; ++ci) {
    *(float4*)&zs[ks * 512 + (c0 + ci) * 32 + b0] =
        make_float4(acc[ci][0], acc[ci][1], acc[ci][2], acc[ci][3]);
  }
  __syncthreads();
  if (tid < 128) {
    int u = tid >> 5;
    int b = tid & 31;
    int L = length[b];
    bool active = sl < L;
    int ug = u0 + u;
    const float* xr = xq + (size_t)sl * 65536 + ug * 32 + b;
    float z[4];
#pragma unroll
    for (int q = 0; q < 4; ++q) {
      float s = xr[(size_t)q * 16384];
#pragma unroll
      for (int p = 0; p < 8; ++p) s += zs[p * 512 + (q * 4 + u) * 32 + b];
      z[q] = s;
    }
    float c_old = cb[ug * 32 + b];
    float h_old = hs[ug * 32 + b];
    float si = 1.f / (1.f + expf(-z[0]));
    float sj = tanhf(z[1]);
    float sf = 1.f / (1.f + expf(-(z[2] + 1.f)));
    float so = 1.f / (1.f + expf(-z[3]));
    float cn = sf * c_old + si * sj;
    float hn = so * tanhf(cn);
    if (active) cb[ug * 32 + b] = cn;
    hTw[ug * 32 + b] = active ? hn : h_old;
    out[((size_t)(b * TT + sl)) * 1024 + dir * 512 + ug] = active ? hn : 0.f;
  }
}

// ---------------- CRF + pooling + final softmax ----------------
__global__ __launch_bounds__(256) void crf_final(
    const float* __restrict__ out1,
    const float* __restrict__ crf_w, const float* __restrict__ crf_b,
    const float* __restrict__ trans,
    const int* __restrict__ length,
    const float* __restrict__ lw, const float* __restrict__ lb,
    float* __restrict__ dout)
{
  __shared__ float e[TT][2];
  __shared__ float pw[TT];
  __shared__ float sv[1024];
  __shared__ float red[256];
  int b = blockIdx.x, tid = threadIdx.x;
  int lane = tid & 63, w = tid >> 6;
  const float* ob = out1 + (size_t)b * TT * 1024;
  for (int t = w; t < TT; t += 4) {
    float a0 = 0.f, a1 = 0.f;
    for (int i = 0; i < 16; ++i) {
      int d = lane + i * 64;
      float v = ob[(size_t)t * 1024 + d];
      a0 += v * crf_w[d * 2];
      a1 += v * crf_w[d * 2 + 1];
    }
    for (int off = 32; off; off >>= 1) {
      a0 += __shfl_down(a0, off);
      a1 += __shfl_down(a1, off);
    }
    if (lane == 0) { e[t][0] = a0 + crf_b[0]; e[t][1] = a1 + crf_b[1]; }
  }
  __syncthreads();
  if (tid == 0) {
    int L = length[b];
    float t00 = trans[0], t01 = trans[1], t10 = trans[2], t11 = trans[3];
    float a0 = e[0][0], a1 = e[0][1];
    {
      float m = fmaxf(a0, a1);
      float e0 = expf(a0 - m), e1 = expf(a1 - m);
      pw[0] = (L > 0) ? (e1 / (e0 + e1)) : 0.f;
    }
    for (int t = 1; t < TT; ++t) {
      if (t < L) {
        float x0 = a0 + t00, y0 = a1 + t10;
        float m0 = fmaxf(x0, y0);
        float n0 = m0 + logf(expf(x0 - m0) + expf(y0 - m0)) + e[t][0];
        float x1 = a0 + t01, y1 = a1 + t11;
        float m1 = fmaxf(x1, y1);
        float n1 = m1 + logf(expf(x1 - m1) + expf(y1 - m1)) + e[t][1];
        a0 = n0; a1 = n1;
        float m = fmaxf(a0, a1);
        float e0 = expf(a0 - m), e1 = expf(a1 - m);
        pw[t] = e1 / (e0 + e1);
      } else {
        pw[t] = 0.f;
      }
    }
  }
  __syncthreads();
  for (int i = 0; i < 4; ++i) {
    int d = tid + i * 256;
    float s = 0.f;
    for (int t = 0; t < TT; ++t) s += pw[t] * ob[(size_t)t * 1024 + d];
    sv[d] = s;
  }
  __syncthreads();
  float v[3];
  for (int c = 0; c < 3; ++c) {
    float s = 0.f;
    for (int i = 0; i < 4; ++i) {
      int d = tid + i * 256;
      s += sv[d] * lw[d * 3 + c];
    }
    red[tid] = s;
    __syncthreads();
    for (int off = 128; off; off >>= 1) {
      if (tid < off) red[tid] += red[tid + off];
      __syncthreads();
    }
    if (tid == 0) v[c] = red[0] + lb[c];
    __syncthreads();
  }
  if (tid == 0) {
    float m = fmaxf(v[0], fmaxf(v[1], v[2]));
    float e0 = expf(v[0] - m), e1 = expf(v[1] - m), e2 = expf(v[2] - m);
    float s = e0 + e1 + e2;
    dout[b * 3 + 0] = e0 / s;
    dout[b * 3 + 1] = e1 / s;
    dout[b * 3 + 2] = e2 / s;
  }
}

static void run_layer(const float* xq_fw, const float* xq_bw,
                      const float* w_fw, const float* w_bw, int din,
                      const int* len, float* out, float* hT, float* cbuf_,
                      int* flags, hipStream_t stream) {
  // zero h ping-pong + c (fallback) + flags
  hipMemsetAsync(hT, 0, (65536 + 32768) * sizeof(float) + 8192 * sizeof(int),
                 stream);
  const float* a0 = xq_fw; const float* a1 = xq_bw;
  const float* a2 = w_fw;  const float* a3 = w_bw;
  int a4 = din; const int* a5 = len; float* a6 = out; float* a7 = hT;
  int* a8 = flags;
  void* args[9] = { &a0, &a1, &a2, &a3, &a4, &a5, &a6, &a7, &a8 };
  hipError_t err = hipLaunchCooperativeKernel(
      reinterpret_cast<const void*>(lstm_persist), dim3(256), dim3(256),
      args, 114688, stream);
  if (err != hipSuccess) {
    for (int t = 0; t < TT; ++t) {
      lstm_step<<<256, 256, 114688, stream>>>(xq_fw, xq_bw, w_fw, w_bw, din,
                                              len, out, hT, cbuf_, t);
    }
  }
}

extern "C" void kernel_launch(void* const* d_in, const int* in_sizes, int n_in,
                              void* d_out, int out_size, void* d_ws, size_t ws_size,
                              hipStream_t stream) {
  (void)in_sizes; (void)n_in; (void)out_size; (void)ws_size;
  const int* ids    = (const int*)d_in[0];
  const int* msk    = (const int*)d_in[1];
  const int* len    = (const int*)d_in[2];
  const float* emb  = (const float*)d_in[3];
  const float* memb = (const float*)d_in[4];
  const float* trans= (const float*)d_in[5];
  const float* w_fw0= (const float*)d_in[6];
  const float* b_fw0= (const float*)d_in[7];
  const float* w_bw0= (const float*)d_in[8];
  const float* b_bw0= (const float*)d_in[9];
  const float* w_fw1= (const float*)d_in[10];
  const float* b_fw1= (const float*)d_in[11];
  const float* w_bw1= (const float*)d_in[12];
  const float* b_bw1= (const float*)d_in[13];
  const float* crf_w= (const float*)d_in[14];
  const float* crf_b= (const float*)d_in[15];
  const float* lw   = (const float*)d_in[16];
  const float* lb   = (const float*)d_in[17];
  float* outp = (float*)d_out;

  float* ws    = (float*)d_ws;
  float* x0    = ws;
  float* xq_fw = x0 + 2867200;
  float* xq_bw = xq_fw + 16777216;
  float* out0  = xq_bw + 16777216;
  float* out1  = out0 + 8388608;
  float* hT    = out1 + 8388608;
  float* cbuf_ = hT + 65536;
  int*   flags = (int*)(cbuf_ + 32768);

  hipFuncSetAttribute(reinterpret_cast<const void*>(lstm_persist),
                      hipFuncAttributeMaxDynamicSharedMemorySize, 114688);
  hipFuncSetAttribute(reinterpret_cast<const void*>(lstm_step),
                      hipFuncAttributeMaxDynamicSharedMemorySize, 114688);

  embed_kernel<<<8192, 256, 0, stream>>>(ids, msk, emb, memb, x0);

  dim3 gg(64, 16);
  gemm_proj_t<<<gg, 256, 0, stream>>>(x0, w_fw0, b_fw0, xq_fw, 350);
  gemm_proj_t<<<gg, 256, 0, stream>>>(x0, w_bw0, b_bw0, xq_bw, 350);

  run_layer(xq_fw, xq_bw, w_fw0, w_bw0, 350, len, out0, hT, cbuf_, flags, stream);

  gemm_proj_t<<<gg, 256, 0, stream>>>(out0, w_fw1, b_fw1, xq_fw, 1024);
  gemm_proj_t<<<gg, 256, 0, stream>>>(out0, w_bw1, b_bw1, xq_bw, 1024);

  run_layer(xq_fw, xq_bw, w_fw1, w_bw1, 1024, len, out1, hT, cbuf_, flags, stream);

  crf_final<<<32, 256, 0, stream>>>(out1, crf_w, crf_b, trans, len, lw, lb, outp);
}

// Round 5
// 3424.931 us; speedup vs baseline: 6.4001x; 1.3577x over previous
//
#include <hip/hip_runtime.h>
#include <hip/hip_bf16.h>
#include <cstdint>
#include <cstddef>

// Problem constants
#define BB 32
#define TT 256
#define HID 512
// ws layout (float units):
//  x0b    : 8192*384 bf16          = 1,572,864 f   [m][384] (K-pad, zeros >=350)
//  wxt0f  : 2048*384 bf16          =   393,216 f   [n][384]
//  wxt0b  : 2048*384 bf16          =   393,216 f
//  wxt1f  : 2048*1024 bf16         = 1,048,576 f
//  wxt1b  : 2048*1024 bf16         = 1,048,576 f
//  xq_fw  : 256*65536 bf16         = 8,388,608 f   [pos][2048][32]
//  xq_bw  : 256*65536 bf16         = 8,388,608 f
//  out0   : 8192*1024 bf16         = 4,194,304 f   [m][1024]
//  out1   : 8192*1024 bf16         = 4,194,304 f
//  hT     : 2*2*512*32 f32         =    65,536 f
//  cbuf   : 2*512*32 f32           =    32,768 f   (fallback only)
//  flags  : 8192 ints

typedef __attribute__((ext_vector_type(8))) short short8v;   // 8 bf16
typedef __attribute__((ext_vector_type(4))) float float4v;

__device__ __forceinline__ float bf2f(unsigned short u) {
  return __uint_as_float(((unsigned int)u) << 16);
}
__device__ __forceinline__ unsigned short f2bf(float f) {
  unsigned int x = __float_as_uint(f);
  x += 0x7fffu + ((x >> 16) & 1u);    // RNE
  return (unsigned short)(x >> 16);
}

// coherent (agent-scope, cache-bypass) ops for cross-WG state
__device__ __forceinline__ void stg1_cohere(float* p, float v) {
  asm volatile("global_store_dword %0, %1, off sc0 sc1"
               :: "v"(p), "v"(v) : "memory");
}
__device__ __forceinline__ void ldg4_cohere_issue(float4& d, const float* p) {
  asm volatile("global_load_dwordx4 %0, %1, off sc0 sc1"
               : "=v"(d) : "v"(p) : "memory");
}
__device__ __forceinline__ void wait_vm0() {
  asm volatile("s_waitcnt vmcnt(0)" ::: "memory");
  __builtin_amdgcn_sched_barrier(0);
}

// ---------------- embedding + concat -> bf16, K-padded to 384 -------------
__global__ __launch_bounds__(256) void embed_kernel(
    const int* __restrict__ ids, const int* __restrict__ msk,
    const float* __restrict__ emb, const float* __restrict__ memb,
    unsigned short* __restrict__ x0b)
{
  int bt = blockIdx.x;            // 0..8191
  int id = ids[bt];
  int m  = msk[bt];
  const float* er = emb  + (size_t)id * 300;
  const float* mr = memb + (size_t)m * 50;
  for (int d = threadIdx.x; d < 384; d += 256) {
    float v = (d < 300) ? er[d] : (d < 350 ? mr[d - 300] : 0.f);
    x0b[(size_t)bt * 384 + d] = f2bf(v);
  }
}

// ---- one-time: wxt[n][k] (bf16, Kpad) = W[k][n] for k < Kreal, else 0 ----
__global__ __launch_bounds__(256) void prep_w(
    const float* __restrict__ W, unsigned short* __restrict__ dst,
    int Kreal, int Kpad)
{
  __shared__ float tile[64][65];
  int tid = threadIdx.x;
  int n0 = blockIdx.x * 64;
  int k0 = blockIdx.y * 64;
#pragma unroll
  for (int i = 0; i < 4; ++i) {
    int e = tid + 256 * i;
    int r = e >> 4, c4 = (e & 15) * 4;
    float4 v = make_float4(0.f, 0.f, 0.f, 0.f);
    if (k0 + r < Kreal) v = *(const float4*)(W + (size_t)(k0 + r) * 2048 + n0 + c4);
    tile[r][c4 + 0] = v.x; tile[r][c4 + 1] = v.y;
    tile[r][c4 + 2] = v.z; tile[r][c4 + 3] = v.w;
  }
  __syncthreads();
  int nl = tid >> 2;
  int kg = (tid & 3) * 16;
  unsigned int pk[4];
#pragma unroll
  for (int jj = 0; jj < 4; ++jj) {
    unsigned short lo = f2bf(tile[kg + jj * 2 + 0][nl]);
    unsigned short hi = f2bf(tile[kg + jj * 2 + 1][nl]);
    pk[jj] = (unsigned int)lo | ((unsigned int)hi << 16);
  }
  // wait: pack order must be k ascending across the 16: jj covers k kg+0..7 only
  // redo: 16 k values -> 8 u32; we store 16 bf16 = 32B = uint4*2? Use 2 stores.
  unsigned int pk2[4];
#pragma unroll
  for (int jj = 0; jj < 4; ++jj) {
    unsigned short lo = f2bf(tile[kg + 8 + jj * 2 + 0][nl]);
    unsigned short hi = f2bf(tile[kg + 8 + jj * 2 + 1][nl]);
    pk2[jj] = (unsigned int)lo | ((unsigned int)hi << 16);
  }
  size_t off = (size_t)(n0 + nl) * Kpad + k0 + kg;
  *(uint4*)(dst + off) = make_uint4(pk[0], pk[1], pk[2], pk[3]);
  *(uint4*)(dst + off + 8) = make_uint4(pk2[0], pk2[1], pk2[2], pk2[3]);
}

// ---- MFMA bf16 GEMM -> xq[pos][2048][32] bf16 ----------------------------
// A_mfma = wxt tile (M-dim = n), B_mfma = x rows {b*256+pos} (N-dim = batch).
// D layout (verified): col = lane&15 -> batch, row = (lane>>4)*4+reg -> n.
__global__ __launch_bounds__(256) void gemm_xproj(
    const unsigned short* __restrict__ A,    // [8192][Kpad] bf16 (x0b or out0)
    const unsigned short* __restrict__ wxt,  // [2048][Kpad] bf16
    const float* __restrict__ bias,          // [2048]
    unsigned short* __restrict__ xq,         // [256][2048][32] bf16
    int Kpad, int nkb)                       // nkb = Kpad/64
{
  __shared__ unsigned short ws_s[128 * 64];  // [n][k] swizzled, 16KB
  __shared__ unsigned short xs_s[32 * 64];   // [b][k] swizzled, 4KB
  __shared__ float bias_s[128];
  int tid = threadIdx.x;
  int lane = tid & 63;
  int w = tid >> 6;
  int pos = blockIdx.x;
  int n0 = blockIdx.y * 128;
  if (tid < 128) bias_s[tid] = bias[n0 + tid];

  float4v acc[2][2];
#pragma unroll
  for (int i = 0; i < 2; ++i)
#pragma unroll
    for (int j = 0; j < 2; ++j) acc[i][j] = (float4v)0.f;

  int brow = tid >> 3;          // 0..31
  int seg = tid & 7;            // 0..7 (16B each)
  for (int kb = 0; kb < nkb; ++kb) {
    int k0 = kb * 64;
    __syncthreads();
    // stage x: 32 rows (batch) x 64 k
    {
      const unsigned short* src = A + (size_t)(brow * 256 + pos) * Kpad + k0 + seg * 8;
      uint4 v = *(const uint4*)src;
      int o = (brow * 128 + seg * 16) ^ ((brow & 7) << 4);
      *(uint4*)((char*)xs_s + o) = v;
    }
    // stage w: 128 rows (n) x 64 k
#pragma unroll
    for (int i = 0; i < 4; ++i) {
      int n = i * 32 + brow;
      const unsigned short* src = wxt + (size_t)(n0 + n) * Kpad + k0 + seg * 8;
      uint4 v = *(const uint4*)src;
      int o = (n * 128 + seg * 16) ^ ((n & 7) << 4);
      *(uint4*)((char*)ws_s + o) = v;
    }
    __syncthreads();
#pragma unroll
    for (int kin = 0; kin < 64; kin += 32) {
      int kl = kin + ((lane >> 4) << 3);   // this lane's 8 contiguous k
      short8v afrag[2], bfrag[2];
#pragma unroll
      for (int nt = 0; nt < 2; ++nt) {
        int nl = w * 32 + nt * 16 + (lane & 15);
        int o = (nl * 128 + kl * 2) ^ ((nl & 7) << 4);
        afrag[nt] = *(const short8v*)((const char*)ws_s + o);
      }
#pragma unroll
      for (int bt = 0; bt < 2; ++bt) {
        int bl = bt * 16 + (lane & 15);
        int o = (bl * 128 + kl * 2) ^ ((bl & 7) << 4);
        bfrag[bt] = *(const short8v*)((const char*)xs_s + o);
      }
#pragma unroll
      for (int nt = 0; nt < 2; ++nt)
#pragma unroll
        for (int bt = 0; bt < 2; ++bt)
          acc[nt][bt] = __builtin_amdgcn_mfma_f32_16x16x32_bf16(
              afrag[nt], bfrag[bt], acc[nt][bt], 0, 0, 0);
    }
  }
  // epilogue: xq[pos][n0+nl][b] bf16
  unsigned short* outp = xq + (size_t)pos * 65536;
#pragma unroll
  for (int nt = 0; nt < 2; ++nt) {
#pragma unroll
    for (int bt = 0; bt < 2; ++bt) {
#pragma unroll
      for (int reg = 0; reg < 4; ++reg) {
        int nl = w * 32 + nt * 16 + ((lane >> 4) << 2) + reg;
        int b = bt * 16 + (lane & 15);
        float v = acc[nt][bt][reg] + bias_s[nl];
        outp[(size_t)(n0 + nl) * 32 + b] = f2bf(v);
      }
    }
  }
}

// ================= persistent bidirectional LSTM layer =================
// (structure frozen from R3; only xq/out dtype changed to bf16)
__global__ __launch_bounds__(256) void lstm_persist(
    const unsigned short* __restrict__ xq_fw, const unsigned short* __restrict__ xq_bw,
    const float* __restrict__ w_fw, const float* __restrict__ w_bw,
    int din,
    const int* __restrict__ length,
    unsigned short* __restrict__ out,   // (B,T,1024) bf16
    float* __restrict__ hT,             // [dir][2][512][32] f32
    int* __restrict__ flags)            // [dir][128][32]
{
  extern __shared__ float smem[];
  float* Wl = smem;              // [512][16]  32KB
  float* hs = smem + 512 * 16;   // [512][32]  64KB
  float* zs = hs + 512 * 32;     // [8][512]   16KB
  int tid = threadIdx.x;
  int wg = blockIdx.x;
  int dir = wg >> 7;
  int u0 = (wg & 127) << 2;
  const float* Wm = dir ? w_bw : w_fw;
  const unsigned short* xq = dir ? xq_bw : xq_fw;
  float* hbase = hT + (size_t)dir * 32768;
  int* dirflags = flags + dir * 4096;
  int* myflag = dirflags + (wg & 127) * 32;

  {
    const float* wbase = Wm + (size_t)din * 2048 + u0;
#pragma unroll
    for (int kk = 0; kk < 2; ++kk) {
      int k = tid * 2 + kk;
      const float* wr = wbase + (size_t)k * 2048;
#pragma unroll
      for (int q = 0; q < 4; ++q) {
        *(float4*)&Wl[k * 16 + q * 4] = *(const float4*)(wr + q * 512);
      }
    }
  }

  int ks = tid >> 5;
  int tile = tid & 31;
  int c0 = (tile & 3) << 2;
  int b0 = (tile >> 2) << 2;
  int kbeg = ks << 6;
  int fu = tid >> 5;
  int fb = tid & 31;
  int L = length[fb & 31];
  float creg = 0.f;

  for (int t = 0; t < TT; ++t) {
    int sl = dir ? (TT - 1 - t) : t;
    const float* hTr = hbase + (size_t)(t & 1) * 16384;
    float* hTw = hbase + (size_t)((t & 1) ^ 1) * 16384;

    float xv0 = 0.f, xv1 = 0.f, xv2 = 0.f, xv3 = 0.f;
    if (tid < 128) {
      const unsigned short* xr = xq + (size_t)sl * 65536 + (u0 + fu) * 32 + fb;
      xv0 = bf2f(xr[0]);
      xv1 = bf2f(xr[16384]);
      xv2 = bf2f(xr[32768]);
      xv3 = bf2f(xr[49152]);
    }

    {
      float4 r0, r1, r2, r3, r4, r5, r6, r7;
      int e0 = tid * 4;
      ldg4_cohere_issue(r0, hTr + e0 + 0 * 1024);
      ldg4_cohere_issue(r1, hTr + e0 + 1 * 1024);
      ldg4_cohere_issue(r2, hTr + e0 + 2 * 1024);
      ldg4_cohere_issue(r3, hTr + e0 + 3 * 1024);
      ldg4_cohere_issue(r4, hTr + e0 + 4 * 1024);
      ldg4_cohere_issue(r5, hTr + e0 + 5 * 1024);
      ldg4_cohere_issue(r6, hTr + e0 + 6 * 1024);
      ldg4_cohere_issue(r7, hTr + e0 + 7 * 1024);
      wait_vm0();
      *(float4*)&hs[e0 + 0 * 1024] = r0;
      *(float4*)&hs[e0 + 1 * 1024] = r1;
      *(float4*)&hs[e0 + 2 * 1024] = r2;
      *(float4*)&hs[e0 + 3 * 1024] = r3;
      *(float4*)&hs[e0 + 4 * 1024] = r4;
      *(float4*)&hs[e0 + 5 * 1024] = r5;
      *(float4*)&hs[e0 + 6 * 1024] = r6;
      *(float4*)&hs[e0 + 7 * 1024] = r7;
      ldg4_cohere_issue(r0, hTr + e0 + 8 * 1024);
      ldg4_cohere_issue(r1, hTr + e0 + 9 * 1024);
      ldg4_cohere_issue(r2, hTr + e0 + 10 * 1024);
      ldg4_cohere_issue(r3, hTr + e0 + 11 * 1024);
      ldg4_cohere_issue(r4, hTr + e0 + 12 * 1024);
      ldg4_cohere_issue(r5, hTr + e0 + 13 * 1024);
      ldg4_cohere_issue(r6, hTr + e0 + 14 * 1024);
      ldg4_cohere_issue(r7, hTr + e0 + 15 * 1024);
      wait_vm0();
      *(float4*)&hs[e0 + 8 * 1024] = r0;
      *(float4*)&hs[e0 + 9 * 1024] = r1;
      *(float4*)&hs[e0 + 10 * 1024] = r2;
      *(float4*)&hs[e0 + 11 * 1024] = r3;
      *(float4*)&hs[e0 + 12 * 1024] = r4;
      *(float4*)&hs[e0 + 13 * 1024] = r5;
      *(float4*)&hs[e0 + 14 * 1024] = r6;
      *(float4*)&hs[e0 + 15 * 1024] = r7;
    }
    __syncthreads();

    float acc[4][4];
#pragma unroll
    for (int i = 0; i < 4; ++i)
#pragma unroll
      for (int j = 0; j < 4; ++j) acc[i][j] = 0.f;
    for (int k = kbeg; k < kbeg + 64; ++k) {
      float4 w4 = *(const float4*)&Wl[k * 16 + c0];
      float4 h4 = *(const float4*)&hs[k * 32 + b0];
      acc[0][0] = fmaf(w4.x, h4.x, acc[0][0]);
      acc[0][1] = fmaf(w4.x, h4.y, acc[0][1]);
      acc[0][2] = fmaf(w4.x, h4.z, acc[0][2]);
      acc[0][3] = fmaf(w4.x, h4.w, acc[0][3]);
      acc[1][0] = fmaf(w4.y, h4.x, acc[1][0]);
      acc[1][1] = fmaf(w4.y, h4.y, acc[1][1]);
      acc[1][2] = fmaf(w4.y, h4.z, acc[1][2]);
      acc[1][3] = fmaf(w4.y, h4.w, acc[1][3]);
      acc[2][0] = fmaf(w4.z, h4.x, acc[2][0]);
      acc[2][1] = fmaf(w4.z, h4.y, acc[2][1]);
      acc[2][2] = fmaf(w4.z, h4.z, acc[2][2]);
      acc[2][3] = fmaf(w4.z, h4.w, acc[2][3]);
      acc[3][0] = fmaf(w4.w, h4.x, acc[3][0]);
      acc[3][1] = fmaf(w4.w, h4.y, acc[3][1]);
      acc[3][2] = fmaf(w4.w, h4.z, acc[3][2]);
      acc[3][3] = fmaf(w4.w, h4.w, acc[3][3]);
    }
#pragma unroll
    for (int ci = 0; ci < 4; ++ci) {
      *(float4*)&zs[ks * 512 + (c0 + ci) * 32 + b0] =
          make_float4(acc[ci][0], acc[ci][1], acc[ci][2], acc[ci][3]);
    }
    __syncthreads();

    if (tid < 128) {
      bool active = sl < L;
      int ug = u0 + fu;
      float z0 = xv0, z1 = xv1, z2 = xv2, z3 = xv3;
#pragma unroll
      for (int p = 0; p < 8; ++p) {
        z0 += zs[p * 512 + (0 * 4 + fu) * 32 + fb];
        z1 += zs[p * 512 + (1 * 4 + fu) * 32 + fb];
        z2 += zs[p * 512 + (2 * 4 + fu) * 32 + fb];
        z3 += zs[p * 512 + (3 * 4 + fu) * 32 + fb];
      }
      float h_old = hs[ug * 32 + fb];
      float si = 1.f / (1.f + expf(-z0));
      float sj = tanhf(z1);
      float sf = 1.f / (1.f + expf(-(z2 + 1.f)));
      float so = 1.f / (1.f + expf(-z3));
      float cn = sf * creg + si * sj;
      float hn = so * tanhf(cn);
      if (active) creg = cn;
      stg1_cohere(&hTw[ug * 32 + fb], active ? hn : h_old);
      out[((size_t)(fb * TT + sl)) * 1024 + dir * 512 + ug] = f2bf(active ? hn : 0.f);
    }

    wait_vm0();
    __syncthreads();
    if (tid == 0) {
      __hip_atomic_store(myflag, t + 1, __ATOMIC_RELAXED,
                         __HIP_MEMORY_SCOPE_AGENT);
    }
    if (tid < 128) {
      int* f = dirflags + tid * 32;
      while (__hip_atomic_load(f, __ATOMIC_RELAXED,
                               __HIP_MEMORY_SCOPE_AGENT) < t + 1) {
        __builtin_amdgcn_s_sleep(1);
      }
    }
    __syncthreads();
  }
}

// ---------------- fallback: one LSTM timestep (per-launch) --------
__global__ __launch_bounds__(256) void lstm_step(
    const unsigned short* __restrict__ xq_fw, const unsigned short* __restrict__ xq_bw,
    const float* __restrict__ w_fw, const float* __restrict__ w_bw,
    int din,
    const int* __restrict__ length,
    unsigned short* __restrict__ out,
    float* __restrict__ hT,
    float* __restrict__ cbuf,
    int t)
{
  extern __shared__ float smem[];
  float* Wl = smem;
  float* hs = smem + 512 * 16;
  float* zs = hs + 512 * 32;
  int tid = threadIdx.x;
  int wg = blockIdx.x;
  int dir = wg >> 7;
  int u0 = (wg & 127) << 2;
  const float* Wm = dir ? w_bw : w_fw;
  const unsigned short* xq = dir ? xq_bw : xq_fw;
  const float* hTr = hT + (size_t)dir * 32768 + (size_t)(t & 1) * 16384;
  float* hTw = hT + (size_t)dir * 32768 + (size_t)((t & 1) ^ 1) * 16384;
  float* cb = cbuf + (size_t)dir * 16384;
  int sl = dir ? (TT - 1 - t) : t;
  {
    const float* wbase = Wm + (size_t)din * 2048 + u0;
#pragma unroll
    for (int kk = 0; kk < 2; ++kk) {
      int k = tid * 2 + kk;
      const float* wr = wbase + (size_t)k * 2048;
#pragma unroll
      for (int q = 0; q < 4; ++q) {
        *(float4*)&Wl[k * 16 + q * 4] = *(const float4*)(wr + q * 512);
      }
    }
  }
#pragma unroll
  for (int i = 0; i < 16; ++i) {
    int e = (tid + i * 256) * 4;
    *(float4*)&hs[e] = *(const float4*)&hTr[e];
  }
  __syncthreads();
  int ks = tid >> 5;
  int tile = tid & 31;
  int c0 = (tile & 3) << 2;
  int b0 = (tile >> 2) << 2;
  float acc[4][4];
#pragma unroll
  for (int i = 0; i < 4; ++i)
#pragma unroll
    for (int j = 0; j < 4; ++j) acc[i][j] = 0.f;
  int kbeg = ks << 6;
  for (int k = kbeg; k < kbeg + 64; ++k) {
    float4 w4 = *(const float4*)&Wl[k * 16 + c0];
    float4 h4 = *(const float4*)&hs[k * 32 + b0];
    acc[0][0] = fmaf(w4.x, h4.x, acc[0][0]);
    acc[0][1] = fmaf(w4.x, h4.y, acc[0][1]);
    acc[0][2] = fmaf(w4.x, h4.z, acc[0][2]);
    acc[0][3] = fmaf(w4.x, h4.w, acc[0][3]);
    acc[1][0] = fmaf(w4.y, h4.x, acc[1][0]);
    acc[1][1] = fmaf(w4.y, h4.y, acc[1][1]);
    acc[1][2] = fmaf(w4.y, h4.z, acc[1][2]);
    acc[1][3] = fmaf(w4.y, h4.w, acc[1][3]);
    acc[2][0] = fmaf(w4.z, h4.x, acc[2][0]);
    acc[2][1] = fmaf(w4.z, h4.y, acc[2][1]);
    acc[2][2] = fmaf(w4.z, h4.z, acc[2][2]);
    acc[2][3] = fmaf(w4.z, h4.w, acc[2][3]);
    acc[3][0] = fmaf(w4.w, h4.x, acc[3][0]);
    acc[3][1] = fmaf(w4.w, h4.y, acc[3][1]);
    acc[3][2] = fmaf(w4.w, h4.z, acc[3][2]);
    acc[3][3] = fmaf(w4.w, h4.w, acc[3][3]);
  }
#pragma unroll
  for (int ci = 0; ci < 4; ++ci) {
    *(float4*)&zs[ks * 512 + (c0 + ci) * 32 + b0] =
        make_float4(acc[ci][0], acc[ci][1], acc[ci][2], acc[ci][3]);
  }
  __syncthreads();
  if (tid < 128) {
    int u = tid >> 5;
    int b = tid & 31;
    int L = length[b];
    bool active = sl < L;
    int ug = u0 + u;
    const unsigned short* xr = xq + (size_t)sl * 65536 + ug * 32 + b;
    float z[4];
#pragma unroll
    for (int q = 0; q < 4; ++q) {
      float s = bf2f(xr[(size_t)q * 16384]);
#pragma unroll
      for (int p = 0; p < 8; ++p) s += zs[p * 512 + (q * 4 + u) * 32 + b];
      z[q] = s;
    }
    float c_old = cb[ug * 32 + b];
    float h_old = hs[ug * 32 + b];
    float si = 1.f / (1.f + expf(-z[0]));
    float sj = tanhf(z[1]);
    float sf = 1.f / (1.f + expf(-(z[2] + 1.f)));
    float so = 1.f / (1.f + expf(-z[3]));
    float cn = sf * c_old + si * sj;
    float hn = so * tanhf(cn);
    if (active) cb[ug * 32 + b] = cn;
    hTw[ug * 32 + b] = active ? hn : h_old;
    out[((size_t)(b * TT + sl)) * 1024 + dir * 512 + ug] = f2bf(active ? hn : 0.f);
  }
}

// ---------------- CRF + pooling + final softmax ----------------
__global__ __launch_bounds__(256) void crf_final(
    const unsigned short* __restrict__ out1,   // (B,T,1024) bf16
    const float* __restrict__ crf_w, const float* __restrict__ crf_b,
    const float* __restrict__ trans,
    const int* __restrict__ length,
    const float* __restrict__ lw, const float* __restrict__ lb,
    float* __restrict__ dout)
{
  __shared__ float e[TT][2];
  __shared__ float pw[TT];
  __shared__ float sv[1024];
  __shared__ float red[256];
  int b = blockIdx.x, tid = threadIdx.x;
  int lane = tid & 63, w = tid >> 6;
  const unsigned short* ob = out1 + (size_t)b * TT * 1024;
  for (int t = w; t < TT; t += 4) {
    float a0 = 0.f, a1 = 0.f;
    for (int i = 0; i < 16; ++i) {
      int d = lane + i * 64;
      float v = bf2f(ob[(size_t)t * 1024 + d]);
      a0 += v * crf_w[d * 2];
      a1 += v * crf_w[d * 2 + 1];
    }
    for (int off = 32; off; off >>= 1) {
      a0 += __shfl_down(a0, off);
      a1 += __shfl_down(a1, off);
    }
    if (lane == 0) { e[t][0] = a0 + crf_b[0]; e[t][1] = a1 + crf_b[1]; }
  }
  __syncthreads();
  if (tid == 0) {
    int L = length[b];
    float t00 = trans[0], t01 = trans[1], t10 = trans[2], t11 = trans[3];
    float a0 = e[0][0], a1 = e[0][1];
    {
      float m = fmaxf(a0, a1);
      float e0 = expf(a0 - m), e1 = expf(a1 - m);
      pw[0] = (L > 0) ? (e1 / (e0 + e1)) : 0.f;
    }
    for (int t = 1; t < TT; ++t) {
      if (t < L) {
        float x0 = a0 + t00, y0 = a1 + t10;
        float m0 = fmaxf(x0, y0);
        float n0 = m0 + logf(expf(x0 - m0) + expf(y0 - m0)) + e[t][0];
        float x1 = a0 + t01, y1 = a1 + t11;
        float m1 = fmaxf(x1, y1);
        float n1 = m1 + logf(expf(x1 - m1) + expf(y1 - m1)) + e[t][1];
        a0 = n0; a1 = n1;
        float m = fmaxf(a0, a1);
        float e0 = expf(a0 - m), e1 = expf(a1 - m);
        pw[t] = e1 / (e0 + e1);
      } else {
        pw[t] = 0.f;
      }
    }
  }
  __syncthreads();
  for (int i = 0; i < 4; ++i) {
    int d = tid + i * 256;
    float s = 0.f;
    for (int t = 0; t < TT; ++t) s += pw[t] * bf2f(ob[(size_t)t * 1024 + d]);
    sv[d] = s;
  }
  __syncthreads();
  float v[3];
  for (int c = 0; c < 3; ++c) {
    float s = 0.f;
    for (int i = 0; i < 4; ++i) {
      int d = tid + i * 256;
      s += sv[d] * lw[d * 3 + c];
    }
    red[tid] = s;
    __syncthreads();
    for (int off = 128; off; off >>= 1) {
      if (tid < off) red[tid] += red[tid + off];
      __syncthreads();
    }
    if (tid == 0) v[c] = red[0] + lb[c];
    __syncthreads();
  }
  if (tid == 0) {
    float m = fmaxf(v[0], fmaxf(v[1], v[2]));
    float e0 = expf(v[0] - m), e1 = expf(v[1] - m), e2 = expf(v[2] - m);
    float s = e0 + e1 + e2;
    dout[b * 3 + 0] = e0 / s;
    dout[b * 3 + 1] = e1 / s;
    dout[b * 3 + 2] = e2 / s;
  }
}

static void run_layer(const unsigned short* xq_fw, const unsigned short* xq_bw,
                      const float* w_fw, const float* w_bw, int din,
                      const int* len, unsigned short* out, float* hT,
                      float* cbuf_, int* flags, hipStream_t stream) {
  hipMemsetAsync(hT, 0, (65536 + 32768) * sizeof(float) + 8192 * sizeof(int),
                 stream);
  const unsigned short* a0 = xq_fw; const unsigned short* a1 = xq_bw;
  const float* a2 = w_fw;  const float* a3 = w_bw;
  int a4 = din; const int* a5 = len; unsigned short* a6 = out; float* a7 = hT;
  int* a8 = flags;
  void* args[9] = { &a0, &a1, &a2, &a3, &a4, &a5, &a6, &a7, &a8 };
  hipError_t err = hipLaunchCooperativeKernel(
      reinterpret_cast<const void*>(lstm_persist), dim3(256), dim3(256),
      args, 114688, stream);
  if (err != hipSuccess) {
    for (int t = 0; t < TT; ++t) {
      lstm_step<<<256, 256, 114688, stream>>>(xq_fw, xq_bw, w_fw, w_bw, din,
                                              len, out, hT, cbuf_, t);
    }
  }
}

extern "C" void kernel_launch(void* const* d_in, const int* in_sizes, int n_in,
                              void* d_out, int out_size, void* d_ws, size_t ws_size,
                              hipStream_t stream) {
  (void)in_sizes; (void)n_in; (void)out_size; (void)ws_size;
  const int* ids    = (const int*)d_in[0];
  const int* msk    = (const int*)d_in[1];
  const int* len    = (const int*)d_in[2];
  const float* emb  = (const float*)d_in[3];
  const float* memb = (const float*)d_in[4];
  const float* trans= (const float*)d_in[5];
  const float* w_fw0= (const float*)d_in[6];
  const float* b_fw0= (const float*)d_in[7];
  const float* w_bw0= (const float*)d_in[8];
  const float* b_bw0= (const float*)d_in[9];
  const float* w_fw1= (const float*)d_in[10];
  const float* b_fw1= (const float*)d_in[11];
  const float* w_bw1= (const float*)d_in[12];
  const float* b_bw1= (const float*)d_in[13];
  const float* crf_w= (const float*)d_in[14];
  const float* crf_b= (const float*)d_in[15];
  const float* lw   = (const float*)d_in[16];
  const float* lb   = (const float*)d_in[17];
  float* outp = (float*)d_out;

  float* ws = (float*)d_ws;
  unsigned short* x0b   = (unsigned short*)(ws);
  unsigned short* wxt0f = (unsigned short*)(ws + 1572864);
  unsigned short* wxt0b = (unsigned short*)(ws + 1966080);
  unsigned short* wxt1f = (unsigned short*)(ws + 2359296);
  unsigned short* wxt1b = (unsigned short*)(ws + 3407872);
  unsigned short* xqf   = (unsigned short*)(ws + 4456448);
  unsigned short* xqb   = (unsigned short*)(ws + 12845056);
  unsigned short* out0b = (unsigned short*)(ws + 21233664);
  unsigned short* out1b = (unsigned short*)(ws + 25427968);
  float* hT    = ws + 29622272;
  float* cbuf_ = ws + 29687808;
  int*   flags = (int*)(ws + 29720576);

  hipFuncSetAttribute(reinterpret_cast<const void*>(lstm_persist),
                      hipFuncAttributeMaxDynamicSharedMemorySize, 114688);
  hipFuncSetAttribute(reinterpret_cast<const void*>(lstm_step),
                      hipFuncAttributeMaxDynamicSharedMemorySize, 114688);

  embed_kernel<<<8192, 256, 0, stream>>>(ids, msk, emb, memb, x0b);

  // one-time weight transpose+cvt (x-projection rows only)
  prep_w<<<dim3(32, 6), 256, 0, stream>>>(w_fw0, wxt0f, 350, 384);
  prep_w<<<dim3(32, 6), 256, 0, stream>>>(w_bw0, wxt0b, 350, 384);
  prep_w<<<dim3(32, 16), 256, 0, stream>>>(w_fw1, wxt1f, 1024, 1024);
  prep_w<<<dim3(32, 16), 256, 0, stream>>>(w_bw1, wxt1b, 1024, 1024);

  gemm_xproj<<<dim3(256, 16), 256, 0, stream>>>(x0b, wxt0f, b_fw0, xqf, 384, 6);
  gemm_xproj<<<dim3(256, 16), 256, 0, stream>>>(x0b, wxt0b, b_bw0, xqb, 384, 6);

  run_layer(xqf, xqb, w_fw0, w_bw0, 350, len, out0b, hT, cbuf_, flags, stream);

  gemm_xproj<<<dim3(256, 16), 256, 0, stream>>>(out0b, wxt1f, b_fw1, xqf, 1024, 16);
  gemm_xproj<<<dim3(256, 16), 256, 0, stream>>>(out0b, wxt1b, b_bw1, xqb, 1024, 16);

  run_layer(xqf, xqb, w_fw1, w_bw1, 1024, len, out1b, hT, cbuf_, flags, stream);

  crf_final<<<32, 256, 0, stream>>>(out1b, crf_w, crf_b, trans, len, lw, lb, outp);
}

// Round 7
// 2202.577 us; speedup vs baseline: 9.9519x; 1.5550x over previous
//
#include <hip/hip_runtime.h>
#include <hip/hip_bf16.h>
#include <cstdint>
#include <cstddef>

// Problem constants
#define BB 32
#define TT 256
#define HID 512
// ws layout (float units):
//  x0b    : 8192*384 bf16   = 1,572,864 f    [m][384]
//  wxt0f  : 2048*384 bf16   =   393,216 f    [n][384]
//  wxt0b  :                 =   393,216 f
//  wxt1f  : 2048*1024 bf16  = 1,048,576 f
//  wxt1b  :                 = 1,048,576 f
//  whT0f  : 2048*512 bf16   =   524,288 f    [col][k] recurrent
//  whT0b  :                 =   524,288 f
//  whT1f  :                 =   524,288 f
//  whT1b  :                 =   524,288 f
//  xqf    : 256*65536 bf16  = 8,388,608 f    [pos][2048][32]
//  xqb    :                 = 8,388,608 f
//  out0b  : 8192*1024 bf16  = 4,194,304 f
//  out1b  :                 = 4,194,304 f
//  hT     : 2*2*32*512 bf16 =    32,768 f    [dir][buf][b][k]
//  cbuf   : 2*512*32 f32    =    32,768 f    (fallback only)
//  flags  : 4096 ints

typedef __attribute__((ext_vector_type(8))) short short8v;   // 8 bf16
typedef __attribute__((ext_vector_type(4))) float float4v;
typedef __attribute__((ext_vector_type(4))) unsigned int uint4v;

__device__ __forceinline__ float bf2f(unsigned short u) {
  return __uint_as_float(((unsigned int)u) << 16);
}
__device__ __forceinline__ unsigned short f2bf(float f) {
  unsigned int x = __float_as_uint(f);
  x += 0x7fffu + ((x >> 16) & 1u);    // RNE
  return (unsigned short)(x >> 16);
}

// coherent (agent-scope, cache-bypass) ops for cross-WG state.
// ext_vector types lower to register quads (same as MFMA operands) — the
// HIP uint4 struct does NOT work as an asm "v" input.
__device__ __forceinline__ void stg4u_cohere(unsigned short* p, uint4v v) {
  asm volatile("global_store_dwordx4 %0, %1, off sc0 sc1"
               :: "v"(p), "v"(v) : "memory");
}
__device__ __forceinline__ void ldg4u_cohere_issue(uint4v& d, const unsigned short* p) {
  asm volatile("global_load_dwordx4 %0, %1, off sc0 sc1"
               : "=v"(d) : "v"(p) : "memory");
}
__device__ __forceinline__ void wait_vm0() {
  asm volatile("s_waitcnt vmcnt(0)" ::: "memory");
  __builtin_amdgcn_sched_barrier(0);
}

// ---------------- embedding + concat -> bf16, K-padded to 384 -------------
__global__ __launch_bounds__(256) void embed_kernel(
    const int* __restrict__ ids, const int* __restrict__ msk,
    const float* __restrict__ emb, const float* __restrict__ memb,
    unsigned short* __restrict__ x0b)
{
  int bt = blockIdx.x;
  int id = ids[bt];
  int m  = msk[bt];
  const float* er = emb  + (size_t)id * 300;
  const float* mr = memb + (size_t)m * 50;
  for (int d = threadIdx.x; d < 384; d += 256) {
    float v = (d < 300) ? er[d] : (d < 350 ? mr[d - 300] : 0.f);
    x0b[(size_t)bt * 384 + d] = f2bf(v);
  }
}

// ---- one-time: dst[n][k] (bf16, Kpad) = W[k][n] for k < Kreal, else 0 ----
__global__ __launch_bounds__(256) void prep_w(
    const float* __restrict__ W, unsigned short* __restrict__ dst,
    int Kreal, int Kpad)
{
  __shared__ float tile[64][65];
  int tid = threadIdx.x;
  int n0 = blockIdx.x * 64;
  int k0 = blockIdx.y * 64;
#pragma unroll
  for (int i = 0; i < 4; ++i) {
    int e = tid + 256 * i;
    int r = e >> 4, c4 = (e & 15) * 4;
    float4 v = make_float4(0.f, 0.f, 0.f, 0.f);
    if (k0 + r < Kreal) v = *(const float4*)(W + (size_t)(k0 + r) * 2048 + n0 + c4);
    tile[r][c4 + 0] = v.x; tile[r][c4 + 1] = v.y;
    tile[r][c4 + 2] = v.z; tile[r][c4 + 3] = v.w;
  }
  __syncthreads();
  int nl = tid >> 2;
  int kg = (tid & 3) * 16;
  unsigned int pk[4], pk2[4];
#pragma unroll
  for (int jj = 0; jj < 4; ++jj) {
    unsigned short lo = f2bf(tile[kg + jj * 2 + 0][nl]);
    unsigned short hi = f2bf(tile[kg + jj * 2 + 1][nl]);
    pk[jj] = (unsigned int)lo | ((unsigned int)hi << 16);
  }
#pragma unroll
  for (int jj = 0; jj < 4; ++jj) {
    unsigned short lo = f2bf(tile[kg + 8 + jj * 2 + 0][nl]);
    unsigned short hi = f2bf(tile[kg + 8 + jj * 2 + 1][nl]);
    pk2[jj] = (unsigned int)lo | ((unsigned int)hi << 16);
  }
  size_t off = (size_t)(n0 + nl) * Kpad + k0 + kg;
  *(uint4*)(dst + off) = make_uint4(pk[0], pk[1], pk[2], pk[3]);
  *(uint4*)(dst + off + 8) = make_uint4(pk2[0], pk2[1], pk2[2], pk2[3]);
}

// ---- MFMA bf16 GEMM -> xq[pos][2048][32] bf16 (R4-validated) -------------
__global__ __launch_bounds__(256) void gemm_xproj(
    const unsigned short* __restrict__ A,    // [8192][Kpad] bf16
    const unsigned short* __restrict__ wxt,  // [2048][Kpad] bf16
    const float* __restrict__ bias,          // [2048]
    unsigned short* __restrict__ xq,         // [256][2048][32] bf16
    int Kpad, int nkb)
{
  __shared__ unsigned short ws_s[128 * 64];
  __shared__ unsigned short xs_s[32 * 64];
  __shared__ float bias_s[128];
  int tid = threadIdx.x;
  int lane = tid & 63;
  int w = tid >> 6;
  int pos = blockIdx.x;
  int n0 = blockIdx.y * 128;
  if (tid < 128) bias_s[tid] = bias[n0 + tid];

  float4v acc[2][2];
#pragma unroll
  for (int i = 0; i < 2; ++i)
#pragma unroll
    for (int j = 0; j < 2; ++j) acc[i][j] = (float4v)0.f;

  int brow = tid >> 3;
  int seg = tid & 7;
  for (int kb = 0; kb < nkb; ++kb) {
    int k0 = kb * 64;
    __syncthreads();
    {
      const unsigned short* src = A + (size_t)(brow * 256 + pos) * Kpad + k0 + seg * 8;
      uint4 v = *(const uint4*)src;
      int o = (brow * 128 + seg * 16) ^ ((brow & 7) << 4);
      *(uint4*)((char*)xs_s + o) = v;
    }
#pragma unroll
    for (int i = 0; i < 4; ++i) {
      int n = i * 32 + brow;
      const unsigned short* src = wxt + (size_t)(n0 + n) * Kpad + k0 + seg * 8;
      uint4 v = *(const uint4*)src;
      int o = (n * 128 + seg * 16) ^ ((n & 7) << 4);
      *(uint4*)((char*)ws_s + o) = v;
    }
    __syncthreads();
#pragma unroll
    for (int kin = 0; kin < 64; kin += 32) {
      int kl = kin + ((lane >> 4) << 3);
      short8v afrag[2], bfrag[2];
#pragma unroll
      for (int nt = 0; nt < 2; ++nt) {
        int nl = w * 32 + nt * 16 + (lane & 15);
        int o = (nl * 128 + kl * 2) ^ ((nl & 7) << 4);
        afrag[nt] = *(const short8v*)((const char*)ws_s + o);
      }
#pragma unroll
      for (int bt = 0; bt < 2; ++bt) {
        int bl = bt * 16 + (lane & 15);
        int o = (bl * 128 + kl * 2) ^ ((bl & 7) << 4);
        bfrag[bt] = *(const short8v*)((const char*)xs_s + o);
      }
#pragma unroll
      for (int nt = 0; nt < 2; ++nt)
#pragma unroll
        for (int bt = 0; bt < 2; ++bt)
          acc[nt][bt] = __builtin_amdgcn_mfma_f32_16x16x32_bf16(
              afrag[nt], bfrag[bt], acc[nt][bt], 0, 0, 0);
    }
  }
  unsigned short* outp = xq + (size_t)pos * 65536;
#pragma unroll
  for (int nt = 0; nt < 2; ++nt) {
#pragma unroll
    for (int bt = 0; bt < 2; ++bt) {
#pragma unroll
      for (int reg = 0; reg < 4; ++reg) {
        int nl = w * 32 + nt * 16 + ((lane >> 4) << 2) + reg;
        int b = bt * 16 + (lane & 15);
        float v = acc[nt][bt][reg] + bias_s[nl];
        outp[(size_t)(n0 + nl) * 32 + b] = f2bf(v);
      }
    }
  }
}

// ================= MFMA bidirectional LSTM recurrence =================
// Grid 128 WGs x 256 thr: wg<64 -> fw, else bw. Each WG owns 8 hidden units
// (32 gate-cols c=q*8+d). W_h slice (32KB bf16) + h broadcast (32KB bf16)
// in LDS, both XOR-swizzled. Per-wave one 16x16 MFMA tile, K=512 (16 MFMA).
// h state crosses WGs as bf16 hT[b][k] via sc0sc1 coherent 16B ops.
// Persistent mode (t1-t0>1): c in registers + flag barrier per step.
// Fallback mode (one step/launch): c in cbuf, no barrier.
__global__ __launch_bounds__(256) void lstm_mfma(
    const unsigned short* __restrict__ xq_fw, const unsigned short* __restrict__ xq_bw,
    const unsigned short* __restrict__ whT_fw, const unsigned short* __restrict__ whT_bw,
    const int* __restrict__ length,
    unsigned short* __restrict__ out,   // (B,T,1024) bf16
    unsigned short* __restrict__ hT,    // [dir][2][32][512] bf16
    float* __restrict__ cbuf,           // [dir][512][32] f32, fallback only
    int* __restrict__ flags,            // [dir][64][32]
    int t0, int t1)
{
  extern __shared__ char smem[];
  // Wl: bytes [0, 32768)       [32 rows c=q*8+d][512 k] bf16, swz ^((row&7)<<4)
  // hs: bytes [32768, 65536)   [32 b][512 k] bf16, same swz
  float* zs = (float*)(smem + 65536);                       // [32][32] f32
  unsigned short* hb_st = (unsigned short*)(smem + 69632);  // [32][8]
  unsigned short* ob_st = (unsigned short*)(smem + 70144);  // [32][8]
  int tid = threadIdx.x;
  int wg = blockIdx.x;
  int dir = wg >> 6;
  int widx = wg & 63;
  int u0 = widx << 3;
  const unsigned short* xq = dir ? xq_bw : xq_fw;
  const unsigned short* whT = dir ? whT_bw : whT_fw;
  unsigned short* hbase = hT + (size_t)dir * 32768;
  int* dirflags = flags + dir * 2048;
  int* myflag = dirflags + widx * 32;

  // ---- stage W_h slice once: LDS row r=q*8+d <- whT[q*512+u0+d][:] ----
  {
    int r = tid >> 3;
    int q = r >> 3, d = r & 7;
    const unsigned short* src = whT + (size_t)(q * 512 + u0 + d) * 512 + (tid & 7) * 8;
    int ob = r * 1024 + (tid & 7) * 16;
    int sw = (r & 7) << 4;
#pragma unroll
    for (int i = 0; i < 8; ++i) {
      uint4 v = *(const uint4*)(src + i * 64);
      *(uint4*)(smem + ((ob + i * 128) ^ sw)) = v;
    }
  }

  // wave/frag constants
  int lane = tid & 63;
  int w = tid >> 6;
  int wr = w >> 1, wc = w & 1;
  int arow = wr * 16 + (lane & 15);
  int bcol = wc * 16 + (lane & 15);
  int chunk16 = (lane >> 4) << 4;     // k byte sub-offset within 64B step
  int asw = (arow & 7) << 4;
  int bsw = (bcol & 7) << 4;
  // finalize constants
  int fu = tid >> 5;                  // unit 0..7
  int fb = tid & 31;                  // batch
  int ug = u0 + fu;
  int L = length[fb];
  float creg = 0.f;

  for (int t = t0; t < t1; ++t) {
    int sl = dir ? (TT - 1 - t) : t;
    const unsigned short* hTr_g = hbase + (size_t)(t & 1) * 16384;
    unsigned short* hTw_g = hbase + (size_t)((t & 1) ^ 1) * 16384;

    // x-projection prefetch (plain loads, L2/IC-cached)
    const unsigned short* xr = xq + (size_t)sl * 65536 + (size_t)ug * 32 + fb;
    float xv0 = bf2f(xr[0]);
    float xv1 = bf2f(xr[16384]);
    float xv2 = bf2f(xr[32768]);
    float xv3 = bf2f(xr[49152]);

    // ---- h broadcast stage: coherent 8x16B -> swizzled LDS ----
    {
      int row = tid >> 3;
      const unsigned short* src = hTr_g + row * 512 + (tid & 7) * 8;
      uint4v r0, r1, r2, r3, r4, r5, r6, r7;
      ldg4u_cohere_issue(r0, src + 0 * 64);
      ldg4u_cohere_issue(r1, src + 1 * 64);
      ldg4u_cohere_issue(r2, src + 2 * 64);
      ldg4u_cohere_issue(r3, src + 3 * 64);
      ldg4u_cohere_issue(r4, src + 4 * 64);
      ldg4u_cohere_issue(r5, src + 5 * 64);
      ldg4u_cohere_issue(r6, src + 6 * 64);
      ldg4u_cohere_issue(r7, src + 7 * 64);
      wait_vm0();
      int ob = 32768 + row * 1024 + (tid & 7) * 16;
      int sw = (row & 7) << 4;
      *(uint4v*)(smem + ((ob + 0 * 128) ^ sw)) = r0;
      *(uint4v*)(smem + ((ob + 1 * 128) ^ sw)) = r1;
      *(uint4v*)(smem + ((ob + 2 * 128) ^ sw)) = r2;
      *(uint4v*)(smem + ((ob + 3 * 128) ^ sw)) = r3;
      *(uint4v*)(smem + ((ob + 4 * 128) ^ sw)) = r4;
      *(uint4v*)(smem + ((ob + 5 * 128) ^ sw)) = r5;
      *(uint4v*)(smem + ((ob + 6 * 128) ^ sw)) = r6;
      *(uint4v*)(smem + ((ob + 7 * 128) ^ sw)) = r7;
    }
    __syncthreads();

    // ---- MFMA: z[32 gate-cols][32 b] = Wl(32x512) @ hs(512x32) ----
    float4v acc = (float4v)0.f;
#pragma unroll
    for (int ks = 0; ks < 16; ++ks) {
      int kb = ks * 64 + chunk16;
      short8v af = *(const short8v*)(smem + (size_t)arow * 1024 + (kb ^ asw));
      short8v bf = *(const short8v*)(smem + 32768 + (size_t)bcol * 1024 + (kb ^ bsw));
      acc = __builtin_amdgcn_mfma_f32_16x16x32_bf16(af, bf, acc, 0, 0, 0);
    }
#pragma unroll
    for (int r = 0; r < 4; ++r) {
      int row = wr * 16 + ((lane >> 4) << 2) + r;
      zs[row * 32 + bcol] = acc[r];
    }
    __syncthreads();

    // ---- finalize: all 256 threads, one (unit,batch) each ----
    {
      bool active = sl < L;
      float z0 = zs[(0 * 8 + fu) * 32 + fb] + xv0;
      float z1 = zs[(1 * 8 + fu) * 32 + fb] + xv1;
      float z2 = zs[(2 * 8 + fu) * 32 + fb] + xv2;
      float z3 = zs[(3 * 8 + fu) * 32 + fb] + xv3;
      // h_old from staged broadcast (bf16)
      int ho = 32768 + fb * 1024 + ((ug * 2) ^ ((fb & 7) << 4));
      float h_old = bf2f(*(const unsigned short*)(smem + ho));
      float c_old = cbuf ? cbuf[dir * 16384 + ug * 32 + fb] : creg;
      float si = 1.f / (1.f + expf(-z0));
      float sj = tanhf(z1);
      float sf = 1.f / (1.f + expf(-(z2 + 1.f)));
      float so = 1.f / (1.f + expf(-z3));
      float cn = sf * c_old + si * sj;
      float hn = so * tanhf(cn);
      if (active) {
        if (cbuf) cbuf[dir * 16384 + ug * 32 + fb] = cn; else creg = cn;
      }
      hb_st[fb * 8 + fu] = f2bf(active ? hn : h_old);
      ob_st[fb * 8 + fu] = f2bf(active ? hn : 0.f);
    }
    __syncthreads();

    if (tid < 32) {
      uint4v hv = *(const uint4v*)(hb_st + tid * 8);
      stg4u_cohere(hTw_g + tid * 512 + u0, hv);
      uint4v ov = *(const uint4v*)(ob_st + tid * 8);
      *(uint4v*)(out + (size_t)(tid * TT + sl) * 1024 + dir * 512 + u0) = ov;
    }

    if (t1 - t0 > 1) {
      wait_vm0();                 // h stores at coherence point (wave 0)
      __syncthreads();
      if (tid == 0) {
        __hip_atomic_store(myflag, t + 1, __ATOMIC_RELAXED,
                           __HIP_MEMORY_SCOPE_AGENT);
      }
      if (tid < 64) {
        int* f = dirflags + tid * 32;
        while (__hip_atomic_load(f, __ATOMIC_RELAXED,
                                 __HIP_MEMORY_SCOPE_AGENT) < t + 1) {
          __builtin_amdgcn_s_sleep(1);
        }
      }
      __syncthreads();
    }
  }
}

// ---------------- CRF + pooling + final softmax ----------------
__global__ __launch_bounds__(256) void crf_final(
    const unsigned short* __restrict__ out1,   // (B,T,1024) bf16
    const float* __restrict__ crf_w, const float* __restrict__ crf_b,
    const float* __restrict__ trans,
    const int* __restrict__ length,
    const float* __restrict__ lw, const float* __restrict__ lb,
    float* __restrict__ dout)
{
  __shared__ float e[TT][2];
  __shared__ float pw[TT];
  __shared__ float sv[1024];
  __shared__ float red[256];
  int b = blockIdx.x, tid = threadIdx.x;
  int lane = tid & 63, w = tid >> 6;
  const unsigned short* ob = out1 + (size_t)b * TT * 1024;
  for (int t = w; t < TT; t += 4) {
    float a0 = 0.f, a1 = 0.f;
    for (int i = 0; i < 16; ++i) {
      int d = lane + i * 64;
      float v = bf2f(ob[(size_t)t * 1024 + d]);
      a0 += v * crf_w[d * 2];
      a1 += v * crf_w[d * 2 + 1];
    }
    for (int off = 32; off; off >>= 1) {
      a0 += __shfl_down(a0, off);
      a1 += __shfl_down(a1, off);
    }
    if (lane == 0) { e[t][0] = a0 + crf_b[0]; e[t][1] = a1 + crf_b[1]; }
  }
  __syncthreads();
  if (tid == 0) {
    int L = length[b];
    float t00 = trans[0], t01 = trans[1], t10 = trans[2], t11 = trans[3];
    float a0 = e[0][0], a1 = e[0][1];
    {
      float m = fmaxf(a0, a1);
      float e0 = expf(a0 - m), e1 = expf(a1 - m);
      pw[0] = (L > 0) ? (e1 / (e0 + e1)) : 0.f;
    }
    for (int t = 1; t < TT; ++t) {
      if (t < L) {
        float x0 = a0 + t00, y0 = a1 + t10;
        float m0 = fmaxf(x0, y0);
        float n0 = m0 + logf(expf(x0 - m0) + expf(y0 - m0)) + e[t][0];
        float x1 = a0 + t01, y1 = a1 + t11;
        float m1 = fmaxf(x1, y1);
        float n1 = m1 + logf(expf(x1 - m1) + expf(y1 - m1)) + e[t][1];
        a0 = n0; a1 = n1;
        float m = fmaxf(a0, a1);
        float e0 = expf(a0 - m), e1 = expf(a1 - m);
        pw[t] = e1 / (e0 + e1);
      } else {
        pw[t] = 0.f;
      }
    }
  }
  __syncthreads();
  for (int i = 0; i < 4; ++i) {
    int d = tid + i * 256;
    float s = 0.f;
    for (int t = 0; t < TT; ++t) s += pw[t] * bf2f(ob[(size_t)t * 1024 + d]);
    sv[d] = s;
  }
  __syncthreads();
  float v[3];
  for (int c = 0; c < 3; ++c) {
    float s = 0.f;
    for (int i = 0; i < 4; ++i) {
      int d = tid + i * 256;
      s += sv[d] * lw[d * 3 + c];
    }
    red[tid] = s;
    __syncthreads();
    for (int off = 128; off; off >>= 1) {
      if (tid < off) red[tid] += red[tid + off];
      __syncthreads();
    }
    if (tid == 0) v[c] = red[0] + lb[c];
    __syncthreads();
  }
  if (tid == 0) {
    float m = fmaxf(v[0], fmaxf(v[1], v[2]));
    float e0 = expf(v[0] - m), e1 = expf(v[1] - m), e2 = expf(v[2] - m);
    float s = e0 + e1 + e2;
    dout[b * 3 + 0] = e0 / s;
    dout[b * 3 + 1] = e1 / s;
    dout[b * 3 + 2] = e2 / s;
  }
}

#define LSTM_LDS 70656

static void run_layer(const unsigned short* xq_fw, const unsigned short* xq_bw,
                      const unsigned short* whT_fw, const unsigned short* whT_bw,
                      const int* len, unsigned short* out, unsigned short* hT,
                      float* cbuf_, int* flags, hipStream_t stream) {
  // zero hT (128KB) + cbuf (128KB) + flags (16KB), contiguous
  (void)hipMemsetAsync(hT, 0, 65536 * 2 + 32768 * 4 + 4096 * 4, stream);
  const unsigned short* a0 = xq_fw; const unsigned short* a1 = xq_bw;
  const unsigned short* a2 = whT_fw; const unsigned short* a3 = whT_bw;
  const int* a4 = len; unsigned short* a5 = out; unsigned short* a6 = hT;
  float* a7 = nullptr; int* a8 = flags; int a9 = 0, a10 = TT;
  void* args[11] = { &a0, &a1, &a2, &a3, &a4, &a5, &a6, &a7, &a8, &a9, &a10 };
  hipError_t err = hipLaunchCooperativeKernel(
      reinterpret_cast<const void*>(lstm_mfma), dim3(128), dim3(256),
      args, LSTM_LDS, stream);
  if (err != hipSuccess) {
    for (int t = 0; t < TT; ++t) {
      lstm_mfma<<<128, 256, LSTM_LDS, stream>>>(
          xq_fw, xq_bw, whT_fw, whT_bw, len, out, hT, cbuf_, flags, t, t + 1);
    }
  }
}

extern "C" void kernel_launch(void* const* d_in, const int* in_sizes, int n_in,
                              void* d_out, int out_size, void* d_ws, size_t ws_size,
                              hipStream_t stream) {
  (void)in_sizes; (void)n_in; (void)out_size; (void)ws_size;
  const int* ids    = (const int*)d_in[0];
  const int* msk    = (const int*)d_in[1];
  const int* len    = (const int*)d_in[2];
  const float* emb  = (const float*)d_in[3];
  const float* memb = (const float*)d_in[4];
  const float* trans= (const float*)d_in[5];
  const float* w_fw0= (const float*)d_in[6];
  const float* b_fw0= (const float*)d_in[7];
  const float* w_bw0= (const float*)d_in[8];
  const float* b_bw0= (const float*)d_in[9];
  const float* w_fw1= (const float*)d_in[10];
  const float* b_fw1= (const float*)d_in[11];
  const float* w_bw1= (const float*)d_in[12];
  const float* b_bw1= (const float*)d_in[13];
  const float* crf_w= (const float*)d_in[14];
  const float* crf_b= (const float*)d_in[15];
  const float* lw   = (const float*)d_in[16];
  const float* lb   = (const float*)d_in[17];
  float* outp = (float*)d_out;

  float* ws = (float*)d_ws;
  unsigned short* x0b   = (unsigned short*)(ws);
  unsigned short* wxt0f = (unsigned short*)(ws + 1572864);
  unsigned short* wxt0b = (unsigned short*)(ws + 1966080);
  unsigned short* wxt1f = (unsigned short*)(ws + 2359296);
  unsigned short* wxt1b = (unsigned short*)(ws + 3407872);
  unsigned short* whT0f = (unsigned short*)(ws + 4456448);
  unsigned short* whT0b = (unsigned short*)(ws + 4980736);
  unsigned short* whT1f = (unsigned short*)(ws + 5505024);
  unsigned short* whT1b = (unsigned short*)(ws + 6029312);
  unsigned short* xqf   = (unsigned short*)(ws + 6553600);
  unsigned short* xqb   = (unsigned short*)(ws + 14942208);
  unsigned short* out0b = (unsigned short*)(ws + 23330816);
  unsigned short* out1b = (unsigned short*)(ws + 27525120);
  unsigned short* hT    = (unsigned short*)(ws + 31719424);
  float* cbuf_ = ws + 31752192;
  int*   flags = (int*)(ws + 31784960);

  (void)hipFuncSetAttribute(reinterpret_cast<const void*>(lstm_mfma),
                            hipFuncAttributeMaxDynamicSharedMemorySize, LSTM_LDS);

  embed_kernel<<<8192, 256, 0, stream>>>(ids, msk, emb, memb, x0b);

  // one-time weight transpose+cvt: x-projection rows [0,din) and h rows [din,din+512)
  prep_w<<<dim3(32, 6), 256, 0, stream>>>(w_fw0, wxt0f, 350, 384);
  prep_w<<<dim3(32, 6), 256, 0, stream>>>(w_bw0, wxt0b, 350, 384);
  prep_w<<<dim3(32, 16), 256, 0, stream>>>(w_fw1, wxt1f, 1024, 1024);
  prep_w<<<dim3(32, 16), 256, 0, stream>>>(w_bw1, wxt1b, 1024, 1024);
  prep_w<<<dim3(32, 8), 256, 0, stream>>>(w_fw0 + (size_t)350 * 2048, whT0f, 512, 512);
  prep_w<<<dim3(32, 8), 256, 0, stream>>>(w_bw0 + (size_t)350 * 2048, whT0b, 512, 512);
  prep_w<<<dim3(32, 8), 256, 0, stream>>>(w_fw1 + (size_t)1024 * 2048, whT1f, 512, 512);
  prep_w<<<dim3(32, 8), 256, 0, stream>>>(w_bw1 + (size_t)1024 * 2048, whT1b, 512, 512);

  gemm_xproj<<<dim3(256, 16), 256, 0, stream>>>(x0b, wxt0f, b_fw0, xqf, 384, 6);
  gemm_xproj<<<dim3(256, 16), 256, 0, stream>>>(x0b, wxt0b, b_bw0, xqb, 384, 6);

  run_layer(xqf, xqb, whT0f, whT0b, len, out0b, hT, cbuf_, flags, stream);

  gemm_xproj<<<dim3(256, 16), 256, 0, stream>>>(out0b, wxt1f, b_fw1, xqf, 1024, 16);
  gemm_xproj<<<dim3(256, 16), 256, 0, stream>>>(out0b, wxt1b, b_bw1, xqb, 1024, 16);

  run_layer(xqf, xqb, whT1f, whT1b, len, out1b, hT, cbuf_, flags, stream);

  crf_final<<<32, 256, 0, stream>>>(out1b, crf_w, crf_b, trans, len, lw, lb, outp);
}